// Round 6
// baseline (1325.109 us; speedup 1.0000x reference)
//
#include <hip/hip_runtime.h>
#include <hip/hip_bf16.h>
#include <math.h>

#define BB 8
#define NN 2048
#define KK 10
#define BN (BB * NN)
#define GCH 64             // point-chunks for fused l4 gathermax+gmax
#define NTILE 16           // col-tiles per row (2048/128)

typedef __attribute__((ext_vector_type(8))) short bf16x8;
typedef __attribute__((ext_vector_type(4))) float f32x4;

__device__ inline unsigned short f2bf(float f) {
    unsigned int u = __float_as_uint(f);
    unsigned int r = u + 0x7fffu + ((u >> 16) & 1u);
    return (unsigned short)(r >> 16);
}
__device__ inline float bf2f(unsigned short h) {
    return __uint_as_float((unsigned int)h << 16);
}

// async global->LDS DMA, 16 B/lane, dest = wave-uniform base + lane*16 [m97]
__device__ __forceinline__ void async16(const void* g, void* l) {
    __builtin_amdgcn_global_load_lds(
        (const __attribute__((address_space(1))) void*)g,
        (__attribute__((address_space(3))) void*)l, 16, 0, 0);
}

// ---------------------------------------------------------------------------
// Layer 0: split x (F=3) into hi/lo bf16 padded to 32, plus row sq-norms.
__global__ void xsplit3_kernel(const float* __restrict__ x,
                               unsigned short* __restrict__ hi,
                               unsigned short* __restrict__ lo,
                               float* __restrict__ sq) {
    int row = blockIdx.x * blockDim.x + threadIdx.x;
    if (row >= BN) return;
    unsigned short hbuf[32], lbuf[32];
#pragma unroll
    for (int f = 0; f < 32; ++f) { hbuf[f] = 0; lbuf[f] = 0; }
    float s = 0.f;
#pragma unroll
    for (int f = 0; f < 3; ++f) {
        float v = x[(size_t)row * 3 + f];
        s += v * v;
        unsigned short h = f2bf(v);
        hbuf[f] = h;
        lbuf[f] = f2bf(v - bf2f(h));
    }
    sq[row] = s;
#pragma unroll
    for (int f = 0; f < 32; f += 8) {
        *(uint4*)&hi[(size_t)row * 32 + f] = *(uint4*)&hbuf[f];
        *(uint4*)&lo[(size_t)row * 32 + f] = *(uint4*)&lbuf[f];
    }
}

// ---------------------------------------------------------------------------
// All 5 layers' WT built in ONE launch (weights are layer-static).
__global__ void wsplit_all_kernel(const float* __restrict__ w0, const float* __restrict__ w1,
                                  const float* __restrict__ w2, const float* __restrict__ w3,
                                  const float* __restrict__ w4, unsigned short* __restrict__ WTall) {
    const int fins[5]  = {3, 64, 128, 256, 512};
    const int fpads[5] = {32, 64, 128, 256, 512};
    const int fouts[5] = {64, 128, 256, 512, 1024};
    const int eoff[6]  = {0, 4096, 20480, 86016, 348160, 1396736};
    const int woff[5]  = {0, 8192, 40960, 172032, 696320};
    int i = blockIdx.x * blockDim.x + threadIdx.x;
    if (i >= 1396736) return;
    int l;
    if (i < eoff[1]) l = 0; else if (i < eoff[2]) l = 1;
    else if (i < eoff[3]) l = 2; else if (i < eoff[4]) l = 3; else l = 4;
    int e = i - eoff[l];
    const float* w = (l == 0) ? w0 : (l == 1) ? w1 : (l == 2) ? w2 : (l == 3) ? w3 : w4;
    int fin = fins[l], fpad = fpads[l], fout = fouts[l];
    unsigned short* WT = WTall + woff[l];
    int op = e % (2 * fout);
    int f = e / (2 * fout);
    float v = 0.f;
    if (f < fin) {
        if (op < fout) v = w[(size_t)f * fout + op] - w[(size_t)(fin + f) * fout + op];
        else v = w[(size_t)(fin + f) * fout + (op - fout)];
    }
    unsigned short h = f2bf(v);
    unsigned short lo = f2bf(v - bf2f(h));
    WT[(size_t)op * (2 * fpad) + f] = h;
    WT[(size_t)op * (2 * fpad) + fpad + f] = lo;
}

// ---------------------------------------------------------------------------
// kNN Gram GEMM + FUSED per-tile top-K (round 6).
// MFMA core verbatim from the validated kernel. Epilogue: instead of writing
// 134 MB of d2 per layer, each block reduces its 128x128 tile to per-row
// top-10 (d,idx) candidates via the LT transpose slab and writes only
// cand[pn][tile][10] (21 MB). Global top-10 of a row contains at most 10
// entries from any tile -> exact. Scans go in ascending col index with
// STRICT < insertion => matches jax top_k (d, index) lexicographic order.
// LT[c*129 + r]: direct-row scan (lane=row, iterate c) banks (c+r)%32 -> 2
// lanes/bank (free); mirror-col scan (lane=c, iterate r) likewise free.
__global__ __launch_bounds__(256) void knn_gram_kernel(
        const unsigned short* __restrict__ xh, const unsigned short* __restrict__ xl,
        const float* __restrict__ sq, float2* __restrict__ cand, int F) {
    int b = blockIdx.y;
    int t = blockIdx.x, ti = 0;
    while (t >= 16 - ti) { t -= 16 - ti; ti++; }
    int tj = ti + t;
    int row0 = ti * 128;
    int col0 = tj * 128;
    const unsigned short* xhb = xh + (size_t)b * NN * F;
    const unsigned short* xlb = xl + (size_t)b * NN * F;
    const float* sqb = sq + (size_t)b * NN;

    __shared__ __align__(16) unsigned char smem_raw[33024];
    unsigned short* Ah = (unsigned short*)smem_raw;
    unsigned short* Al = Ah + 128 * 32;
    unsigned short* Bh = Al + 128 * 32;
    unsigned short* Bl = Bh + 128 * 32;
    float* LT = (float*)smem_raw;

    int tid = threadIdx.x;
    int lane = tid & 63;
    int wave = tid >> 6;
    int wr = (wave >> 1) * 64, wc = (wave & 1) * 64;
    int l15 = lane & 15, kq = lane >> 4;
    int rsub = lane >> 2;
    int csub = (((lane & 3) ^ ((lane >> 3) & 3))) * 8;
    int kqs = (kq ^ ((l15 >> 1) & 3)) * 8;

    f32x4 acc[4][4];
#pragma unroll
    for (int mt = 0; mt < 4; ++mt)
#pragma unroll
        for (int nt = 0; nt < 4; ++nt) acc[mt][nt] = (f32x4){0.f, 0.f, 0.f, 0.f};

    for (int kc = 0; kc < F; kc += 32) {
        __syncthreads();
#pragma unroll
        for (int j = 0; j < 2; ++j) {
            int row = wave * 32 + j * 16 + rsub;
            int dsto = wave * 1024 + j * 512;
            async16(xhb + (size_t)(row0 + row) * F + kc + csub, Ah + dsto);
            async16(xlb + (size_t)(row0 + row) * F + kc + csub, Al + dsto);
            async16(xhb + (size_t)(col0 + row) * F + kc + csub, Bh + dsto);
            async16(xlb + (size_t)(col0 + row) * F + kc + csub, Bl + dsto);
        }
        __syncthreads();
        bf16x8 bh[4], bl[4];
#pragma unroll
        for (int t4 = 0; t4 < 4; ++t4) {
            bh[t4] = *(const bf16x8*)&Bh[(wc + t4 * 16 + l15) * 32 + kqs];
            bl[t4] = *(const bf16x8*)&Bl[(wc + t4 * 16 + l15) * 32 + kqs];
        }
#pragma unroll
        for (int mt = 0; mt < 4; ++mt) {
            bf16x8 ah = *(const bf16x8*)&Ah[(wr + mt * 16 + l15) * 32 + kqs];
            bf16x8 al = *(const bf16x8*)&Al[(wr + mt * 16 + l15) * 32 + kqs];
#pragma unroll
            for (int nt = 0; nt < 4; ++nt) {
                acc[mt][nt] = __builtin_amdgcn_mfma_f32_16x16x32_bf16(ah, bh[nt], acc[mt][nt], 0, 0, 0);
                acc[mt][nt] = __builtin_amdgcn_mfma_f32_16x16x32_bf16(al, bh[nt], acc[mt][nt], 0, 0, 0);
                acc[mt][nt] = __builtin_amdgcn_mfma_f32_16x16x32_bf16(ah, bl[nt], acc[mt][nt], 0, 0, 0);
            }
        }
    }

    // acc -> d2 (registers only; no global d2)
#pragma unroll
    for (int mt = 0; mt < 4; ++mt) {
        int rbase = row0 + wr + mt * 16 + kq * 4;
#pragma unroll
        for (int nt = 0; nt < 4; ++nt) {
            int cc = wc + nt * 16 + l15;
            float sqc = sqb[col0 + cc];
#pragma unroll
            for (int r = 0; r < 4; ++r)
                acc[mt][nt][r] = (sqb[rbase + r] + sqc) - 2.f * acc[mt][nt][r];
        }
    }

    // ---- stage-1 per-tile top-K via LT slab, two col-halves
    float dD[KK]; int iD[KK];
    if (tid < 128) {
#pragma unroll
        for (int k = 0; k < KK; ++k) { dD[k] = INFINITY; iD[k] = 0x7fffffff; }
    }
#pragma unroll
    for (int h = 0; h < 2; ++h) {
        __syncthreads();
        if ((wave & 1) == h) {
#pragma unroll
            for (int mt = 0; mt < 4; ++mt)
#pragma unroll
                for (int nt = 0; nt < 4; ++nt)
#pragma unroll
                    for (int r = 0; r < 4; ++r)
                        LT[(nt * 16 + l15) * 129 + (wr + mt * 16 + kq * 4 + r)] =
                            acc[mt][nt][r];
        }
        __syncthreads();
        if (tid < 128) {
            // direct rows: row = tid, scan this half's 64 cols (ascending idx)
            int row = tid;
            int cb = col0 + h * 64;
#pragma unroll 8
            for (int c = 0; c < 64; ++c) {
                float d = LT[c * 129 + row];
                if (d < dD[KK - 1]) {
                    dD[KK - 1] = d; iD[KK - 1] = cb + c;
#pragma unroll
                    for (int s = KK - 1; s > 0; --s)
                        if (dD[s] < dD[s - 1]) {
                            float td = dD[s]; dD[s] = dD[s - 1]; dD[s - 1] = td;
                            int tx = iD[s]; iD[s] = iD[s - 1]; iD[s - 1] = tx;
                        }
                }
            }
        } else if (tid < 192 && ti != tj) {
            // mirror rows: this half's col (col0+h*64+cq), neighbors = rows
            int cq = tid - 128;
            float dM[KK]; int iM[KK];
#pragma unroll
            for (int k = 0; k < KK; ++k) { dM[k] = INFINITY; iM[k] = 0x7fffffff; }
#pragma unroll 8
            for (int r = 0; r < 128; ++r) {
                float d = LT[cq * 129 + r];
                if (d < dM[KK - 1]) {
                    dM[KK - 1] = d; iM[KK - 1] = row0 + r;
#pragma unroll
                    for (int s = KK - 1; s > 0; --s)
                        if (dM[s] < dM[s - 1]) {
                            float td = dM[s]; dM[s] = dM[s - 1]; dM[s - 1] = td;
                            int tx = iM[s]; iM[s] = iM[s - 1]; iM[s - 1] = tx;
                        }
                }
            }
            float2* cw = cand + ((size_t)b * NN + col0 + h * 64 + cq) * (NTILE * KK)
                              + ti * KK;
#pragma unroll
            for (int k = 0; k < KK; ++k)
                cw[k] = make_float2(dM[k], __int_as_float(iM[k]));
        }
    }
    if (tid < 128) {
        float2* cw = cand + ((size_t)b * NN + row0 + tid) * (NTILE * KK)
                          + tj * KK;
#pragma unroll
        for (int k = 0; k < KK; ++k)
            cw[k] = make_float2(dD[k], __int_as_float(iD[k]));
    }
}

// ---------------------------------------------------------------------------
// kNN merge (round 6): wave-per-row top-10 of 160 candidates (16 tiles x 10).
// Same (d, index) lexicographic extraction as the validated select kernel.
__global__ __launch_bounds__(256) void knn_merge_kernel(
        const float2* __restrict__ cand, int* __restrict__ idx) {
    int row = blockIdx.x * 4 + (threadIdx.x >> 6);
    int lane = threadIdx.x & 63;
    const float2* cp = cand + (size_t)row * (NTILE * KK);

    float d[3]; int ix[3];
    float2 e0 = cp[lane];
    float2 e1 = cp[lane + 64];
    d[0] = e0.x; ix[0] = __float_as_int(e0.y);
    d[1] = e1.x; ix[1] = __float_as_int(e1.y);
    if (lane < 32) {
        float2 e2 = cp[lane + 128];
        d[2] = e2.x; ix[2] = __float_as_int(e2.y);
    } else { d[2] = INFINITY; ix[2] = 0x7fffffff; }

    // sort3 by (d, ix) lexicographic
#define CSW(a, b) if (d[b] < d[a] || (d[b] == d[a] && ix[b] < ix[a])) { \
        float td = d[a]; d[a] = d[b]; d[b] = td; \
        int tx = ix[a]; ix[a] = ix[b]; ix[b] = tx; }
    CSW(0, 1) CSW(1, 2) CSW(0, 1)
#undef CSW

    int h = 0;
    int mywin = 0;
    for (int s = 0; s < KK; ++s) {
        float dd = (h < 3) ? d[h] : INFINITY;
        int ii = (h < 3) ? ix[h] : 0x7fffffff;
        float d0 = dd; int i0 = ii;
#pragma unroll
        for (int off = 32; off > 0; off >>= 1) {
            float od = __shfl_xor(dd, off);
            int oi = __shfl_xor(ii, off);
            if (od < dd || (od == dd && oi < ii)) { dd = od; ii = oi; }
        }
        if (lane == s) mywin = ii;
        if (h < 3 && i0 == ii && d0 == dd) h++;
    }
    if (lane < KK) idx[(size_t)row * KK + lane] = mywin;
}

// ---------------------------------------------------------------------------
// MFMA GEMM (validated rounds 16/17/20, verbatim): single-pass 4-tile staging
// + XOR swizzle. LDS 32 KB. Used for layers 0,1,2,4 (full-GPU 128^2 grids).
__global__ __launch_bounds__(256) void gemm2_mfma_kernel(
        const unsigned short* __restrict__ XSh, const unsigned short* __restrict__ XSl,
        const unsigned short* __restrict__ WT, const float* __restrict__ bias,
        float* __restrict__ Aout, float* __restrict__ Tout, int fin, int fout) {
    int m0 = blockIdx.x * 128;
    int n0 = blockIdx.y * 128;
    __shared__ __align__(16) unsigned short AsB[4 * 128 * 32];   // 32 KB
    unsigned short* Ah = AsB;
    unsigned short* Al = Ah + 128 * 32;
    unsigned short* Bh = Al + 128 * 32;
    unsigned short* Bl = Bh + 128 * 32;

    int tid = threadIdx.x;
    int lane = tid & 63;
    int wave = tid >> 6;
    int wr = (wave >> 1) * 64, wc = (wave & 1) * 64;
    int l15 = lane & 15, kq = lane >> 4;
    int rsub = lane >> 2;
    int csub = (((lane & 3) ^ ((lane >> 3) & 3))) * 8;
    int kqs = (kq ^ ((l15 >> 1) & 3)) * 8;
    int w2f = 2 * fin;

    f32x4 acc[4][4];
#pragma unroll
    for (int mt = 0; mt < 4; ++mt)
#pragma unroll
        for (int nt = 0; nt < 4; ++nt) acc[mt][nt] = (f32x4){0.f, 0.f, 0.f, 0.f};

    for (int kc = 0; kc < fin; kc += 32) {
        __syncthreads();
#pragma unroll
        for (int j = 0; j < 2; ++j) {
            int row = wave * 32 + j * 16 + rsub;
            int dsto = wave * 1024 + j * 512;
            async16(XSh + (size_t)(m0 + row) * fin + kc + csub, Ah + dsto);
            async16(XSl + (size_t)(m0 + row) * fin + kc + csub, Al + dsto);
            async16(WT + (size_t)(n0 + row) * w2f + kc + csub, Bh + dsto);
            async16(WT + (size_t)(n0 + row) * w2f + fin + kc + csub, Bl + dsto);
        }
        __syncthreads();
        bf16x8 bh[4], bl[4];
#pragma unroll
        for (int t = 0; t < 4; ++t) {
            bh[t] = *(const bf16x8*)&Bh[(wc + t * 16 + l15) * 32 + kqs];
            bl[t] = *(const bf16x8*)&Bl[(wc + t * 16 + l15) * 32 + kqs];
        }
#pragma unroll
        for (int mt = 0; mt < 4; ++mt) {
            bf16x8 ah = *(const bf16x8*)&Ah[(wr + mt * 16 + l15) * 32 + kqs];
            bf16x8 al = *(const bf16x8*)&Al[(wr + mt * 16 + l15) * 32 + kqs];
#pragma unroll
            for (int nt = 0; nt < 4; ++nt) {
                acc[mt][nt] = __builtin_amdgcn_mfma_f32_16x16x32_bf16(ah, bh[nt], acc[mt][nt], 0, 0, 0);
                acc[mt][nt] = __builtin_amdgcn_mfma_f32_16x16x32_bf16(al, bh[nt], acc[mt][nt], 0, 0, 0);
                acc[mt][nt] = __builtin_amdgcn_mfma_f32_16x16x32_bf16(ah, bl[nt], acc[mt][nt], 0, 0, 0);
            }
        }
    }
#pragma unroll
    for (int mt = 0; mt < 4; ++mt) {
        int mbase = m0 + wr + mt * 16 + kq * 4;
#pragma unroll
        for (int nt = 0; nt < 4; ++nt) {
            int oc = n0 + wc + nt * 16 + l15;
            f32x4 c = acc[mt][nt];
            if (oc < fout) {
                float bv = bias[oc];
#pragma unroll
                for (int r = 0; r < 4; ++r)
                    Aout[(size_t)(mbase + r) * fout + oc] = c[r] + bv;
            } else {
                int o2 = oc - fout;
#pragma unroll
                for (int r = 0; r < 4; ++r)
                    Tout[(size_t)(mbase + r) * fout + o2] = c[r];
            }
        }
    }
}

// ---------------------------------------------------------------------------
// 256^2-tile 8-phase pipelined GEMM (round-1 verbatim, refcheck'd) — layer 3
// only (grid 256 = 1 block/CU; measured -47 us vs 128^2 at l3 in R5).
__device__ __forceinline__ const unsigned short* tbaseA(
        const unsigned short* XSh, const unsigned short* XSl, int F, int t) {
    int ko = t * 64;
    if (ko < F) return XSh + ko;
    if (ko < 2 * F) return XSl + (ko - F);
    return XSh + (ko - 2 * F);
}
__device__ __forceinline__ const unsigned short* tbaseB(
        const unsigned short* WT, int F, int t) {
    int ko = t * 64;
    if (ko < F) return WT + ko;
    if (ko < 2 * F) return WT + (ko - F);       // hi again
    return WT + F + (ko - 2 * F);               // lo half of the row
}

#define GBAR() asm volatile("s_barrier" ::: "memory")

__global__ __launch_bounds__(512, 2) void gemm2_8ph_kernel(
        const unsigned short* __restrict__ XSh, const unsigned short* __restrict__ XSl,
        const unsigned short* __restrict__ WT, const float* __restrict__ bias,
        float* __restrict__ Aout, float* __restrict__ Tout, int F, int fout, int nby) {
    __shared__ __align__(16) unsigned short Lds[65536];   // 128 KiB

    int nwg = gridDim.x;
    int bid = blockIdx.x;
    int q = nwg >> 3;
    int swz = (bid & 7) * q + (bid >> 3);
    int by = swz % nby;
    int bx = swz / nby;
    int m0 = bx * 256, n0 = by * 256;

    int tid = threadIdx.x;
    int lane = tid & 63;
    int wave = tid >> 6;
    int mw = wave >> 2;
    int nw = wave & 3;
    int l15 = lane & 15, kq = lane >> 4;
    int rx7 = l15 & 7;

    int isA = (wave < 4);
    size_t rowmul = isA ? (size_t)F : (size_t)(2 * F);
    int orgn = isA ? m0 : n0;
    int r8 = lane >> 3;
    int cb8 = ((lane & 7) ^ r8) * 8;
    int subb = (wave & 3) * 8;
    int ldsoA = isA ? 0 : 16384;

    int nt = (3 * F) >> 6;

    f32x4 acc[8][4];
#pragma unroll
    for (int mt = 0; mt < 8; ++mt)
#pragma unroll
        for (int nn = 0; nn < 4; ++nn) acc[mt][nn] = (f32x4){0.f, 0.f, 0.f, 0.f};

    auto stage = [&](const unsigned short* tb, int par, int j) {
        int sub = subb + j;
        async16(tb + (size_t)(orgn + sub * 8 + r8) * rowmul + cb8,
                Lds + par * 32768 + ldsoA + sub * 512);
    };

    {
        const unsigned short* t0 = isA ? tbaseA(XSh, XSl, F, 0) : tbaseB(WT, F, 0);
        const unsigned short* t1 = isA ? tbaseA(XSh, XSl, F, 1) : tbaseB(WT, F, 1);
#pragma unroll
        for (int j = 0; j < 8; ++j) stage(t0, 0, j);
#pragma unroll
        for (int j = 0; j < 4; ++j) stage(t1, 1, j);
    }
    asm volatile("s_waitcnt vmcnt(4)" ::: "memory");
    GBAR();

    for (int t = 0; t < nt; ++t) {
        const unsigned short* Ab = Lds + (t & 1) * 32768;
        const unsigned short* Bb = Ab + 16384;
        bool s1 = (t + 1 < nt), s2 = (t + 2 < nt);
        const unsigned short* tb1 = s1 ? (isA ? tbaseA(XSh, XSl, F, t + 1)
                                              : tbaseB(WT, F, t + 1)) : XSh;
        const unsigned short* tb2 = s2 ? (isA ? tbaseA(XSh, XSl, F, t + 2)
                                              : tbaseB(WT, F, t + 2)) : XSh;
        int p1 = (t + 1) & 1, p0 = t & 1;

        bf16x8 aF[4][2], bA[2][2], bB[2][2];

#pragma unroll
        for (int mt = 0; mt < 4; ++mt)
#pragma unroll
            for (int kf = 0; kf < 2; ++kf)
                aF[mt][kf] = *(const bf16x8*)&Ab[(mw * 128 + mt * 16 + l15) * 64 +
                                                 ((kf * 4 + kq) ^ rx7) * 8];
#pragma unroll
        for (int nn = 0; nn < 2; ++nn)
#pragma unroll
            for (int kf = 0; kf < 2; ++kf)
                bA[nn][kf] = *(const bf16x8*)&Bb[(nw * 64 + nn * 16 + l15) * 64 +
                                                 ((kf * 4 + kq) ^ rx7) * 8];
        if (s1) { stage(tb1, p1, 4); stage(tb1, p1, 5); }
        GBAR();
        __builtin_amdgcn_s_setprio(1);
#pragma unroll
        for (int mt = 0; mt < 4; ++mt)
#pragma unroll
            for (int nn = 0; nn < 2; ++nn) {
                acc[mt][nn] = __builtin_amdgcn_mfma_f32_16x16x32_bf16(aF[mt][0], bA[nn][0], acc[mt][nn], 0, 0, 0);
                acc[mt][nn] = __builtin_amdgcn_mfma_f32_16x16x32_bf16(aF[mt][1], bA[nn][1], acc[mt][nn], 0, 0, 0);
            }
        __builtin_amdgcn_s_setprio(0);
        GBAR();

#pragma unroll
        for (int nn = 0; nn < 2; ++nn)
#pragma unroll
            for (int kf = 0; kf < 2; ++kf)
                bB[nn][kf] = *(const bf16x8*)&Bb[(nw * 64 + (nn + 2) * 16 + l15) * 64 +
                                                 ((kf * 4 + kq) ^ rx7) * 8];
        if (s1) { stage(tb1, p1, 6); stage(tb1, p1, 7); }
        GBAR();
        __builtin_amdgcn_s_setprio(1);
#pragma unroll
        for (int mt = 0; mt < 4; ++mt)
#pragma unroll
            for (int nn = 0; nn < 2; ++nn) {
                acc[mt][nn + 2] = __builtin_amdgcn_mfma_f32_16x16x32_bf16(aF[mt][0], bB[nn][0], acc[mt][nn + 2], 0, 0, 0);
                acc[mt][nn + 2] = __builtin_amdgcn_mfma_f32_16x16x32_bf16(aF[mt][1], bB[nn][1], acc[mt][nn + 2], 0, 0, 0);
            }
        __builtin_amdgcn_s_setprio(0);
        GBAR();

#pragma unroll
        for (int mt = 0; mt < 4; ++mt)
#pragma unroll
            for (int kf = 0; kf < 2; ++kf)
                aF[mt][kf] = *(const bf16x8*)&Ab[(mw * 128 + (mt + 4) * 16 + l15) * 64 +
                                                 ((kf * 4 + kq) ^ rx7) * 8];
        GBAR();
        __builtin_amdgcn_s_setprio(1);
#pragma unroll
        for (int mt = 0; mt < 4; ++mt)
#pragma unroll
            for (int nn = 0; nn < 2; ++nn) {
                acc[mt + 4][nn] = __builtin_amdgcn_mfma_f32_16x16x32_bf16(aF[mt][0], bA[nn][0], acc[mt + 4][nn], 0, 0, 0);
                acc[mt + 4][nn] = __builtin_amdgcn_mfma_f32_16x16x32_bf16(aF[mt][1], bA[nn][1], acc[mt + 4][nn], 0, 0, 0);
            }
        __builtin_amdgcn_s_setprio(0);
        GBAR();

        if (s2) { stage(tb2, p0, 0); stage(tb2, p0, 1); stage(tb2, p0, 2); stage(tb2, p0, 3); }
        GBAR();
        __builtin_amdgcn_s_setprio(1);
#pragma unroll
        for (int mt = 0; mt < 4; ++mt)
#pragma unroll
            for (int nn = 0; nn < 2; ++nn) {
                acc[mt + 4][nn + 2] = __builtin_amdgcn_mfma_f32_16x16x32_bf16(aF[mt][0], bB[nn][0], acc[mt + 4][nn + 2], 0, 0, 0);
                acc[mt + 4][nn + 2] = __builtin_amdgcn_mfma_f32_16x16x32_bf16(aF[mt][1], bB[nn][1], acc[mt + 4][nn + 2], 0, 0, 0);
            }
        __builtin_amdgcn_s_setprio(0);
        if (s2)      asm volatile("s_waitcnt vmcnt(4)" ::: "memory");
        else if (s1) asm volatile("s_waitcnt vmcnt(0)" ::: "memory");
        GBAR();
    }

#pragma unroll
    for (int mt = 0; mt < 8; ++mt) {
        int mbase = m0 + mw * 128 + mt * 16 + kq * 4;
#pragma unroll
        for (int nn = 0; nn < 4; ++nn) {
            int oc = n0 + nw * 64 + nn * 16 + l15;
            f32x4 c = acc[mt][nn];
            if (oc < fout) {
                float bv = bias[oc];
#pragma unroll
                for (int r = 0; r < 4; ++r)
                    Aout[(size_t)(mbase + r) * fout + oc] = c[r] + bv;
            } else {
                int o2 = oc - fout;
#pragma unroll
                for (int r = 0; r < 4; ++r)
                    Tout[(size_t)(mbase + r) * fout + o2] = c[r];
            }
        }
    }
}

// ---------------------------------------------------------------------------
// FUSED gathermax (layers 0-3): wave-per-row; writes bf16 splits + sq only.
__global__ __launch_bounds__(256) void gathermax_fused_kernel(
        const float* __restrict__ A, const float* __restrict__ T,
        const int* __restrict__ idx, unsigned short* __restrict__ hi,
        unsigned short* __restrict__ lo, float* __restrict__ sq, int shift) {
    int b = blockIdx.y;
    int wave = threadIdx.x >> 6;
    int lane = threadIdx.x & 63;
    int pnl = blockIdx.x * 4 + wave;
    int pn = (b << 11) + pnl;
    int fout = 1 << shift;
    int nf4 = fout >> 2;
    const float* Tb = T + ((size_t)b << 11) * fout;
    const int* ip = idx + (size_t)pn * KK;
    int j[KK];
#pragma unroll
    for (int k = 0; k < KK; ++k) j[k] = ip[k];

    float s = 0.f;
    for (int f4 = lane; f4 < nf4; f4 += 64) {
        int o = f4 * 4;
        float4 m = {-INFINITY, -INFINITY, -INFINITY, -INFINITY};
#pragma unroll
        for (int k = 0; k < KK; ++k) {
            float4 t = *(const float4*)&Tb[(size_t)j[k] * fout + o];
            m.x = fmaxf(m.x, t.x); m.y = fmaxf(m.y, t.y);
            m.z = fmaxf(m.z, t.z); m.w = fmaxf(m.w, t.w);
        }
        float4 a = *(const float4*)&A[(size_t)pn * fout + o];
        float h4[4];
        h4[0] = a.x + m.x; h4[1] = a.y + m.y; h4[2] = a.z + m.z; h4[3] = a.w + m.w;
        uint2 uh, ul;
        unsigned short hs[4], ls[4];
#pragma unroll
        for (int q = 0; q < 4; ++q) {
            float h = h4[q] > 0.f ? h4[q] : 0.2f * h4[q];
            s += h * h;
            unsigned short hh = f2bf(h);
            hs[q] = hh;
            ls[q] = f2bf(h - bf2f(hh));
        }
        uh.x = (unsigned)hs[0] | ((unsigned)hs[1] << 16);
        uh.y = (unsigned)hs[2] | ((unsigned)hs[3] << 16);
        ul.x = (unsigned)ls[0] | ((unsigned)ls[1] << 16);
        ul.y = (unsigned)ls[2] | ((unsigned)ls[3] << 16);
        *(uint2*)&hi[(size_t)pn * fout + o] = uh;
        *(uint2*)&lo[(size_t)pn * fout + o] = ul;
    }
#pragma unroll
    for (int off = 32; off > 0; off >>= 1) s += __shfl_down(s, off);
    if (lane == 0) sq[pn] = s;
}

// ---------------------------------------------------------------------------
// FUSED l4 gathermax + gmax pass 1 (validated round 20).
__global__ __launch_bounds__(256) void gathermax_gmax_kernel(
        const float* __restrict__ A, const float* __restrict__ T,
        const int* __restrict__ idx, float* __restrict__ gp) {
    int chunk = blockIdx.x;
    int b = blockIdx.y;
    int o = threadIdx.x * 4;
    const float* Tb = T + ((size_t)b << 11) * 1024;
    float4 gm = {-INFINITY, -INFINITY, -INFINITY, -INFINITY};
    for (int p = 0; p < NN / GCH; ++p) {
        int pnl = chunk * (NN / GCH) + p;
        int pn = (b << 11) + pnl;
        const int* ip = idx + (size_t)pn * KK;
        float4 m = {-INFINITY, -INFINITY, -INFINITY, -INFINITY};
#pragma unroll
        for (int k = 0; k < KK; ++k) {
            int j = ip[k];
            float4 t = *(const float4*)&Tb[(size_t)j * 1024 + o];
            m.x = fmaxf(m.x, t.x); m.y = fmaxf(m.y, t.y);
            m.z = fmaxf(m.z, t.z); m.w = fmaxf(m.w, t.w);
        }
        float4 a = *(const float4*)&A[(size_t)pn * 1024 + o];
        float4 h;
        h.x = a.x + m.x; h.y = a.y + m.y; h.z = a.z + m.z; h.w = a.w + m.w;
        h.x = h.x > 0.f ? h.x : 0.2f * h.x;
        h.y = h.y > 0.f ? h.y : 0.2f * h.y;
        h.z = h.z > 0.f ? h.z : 0.2f * h.z;
        h.w = h.w > 0.f ? h.w : 0.2f * h.w;
        gm.x = fmaxf(gm.x, h.x); gm.y = fmaxf(gm.y, h.y);
        gm.z = fmaxf(gm.z, h.z); gm.w = fmaxf(gm.w, h.w);
    }
    *(float4*)&gp[((size_t)chunk * BB + b) * 1024 + o] = gm;
}

// ---------------------------------------------------------------------------
// Parallel tail: gmax2 (coalesced) then wave-per-output MLP stages.
__global__ void gmax2_kernel(const float* __restrict__ gp, float* __restrict__ g) {
    int i = blockIdx.x * 256 + threadIdx.x;      // 0..8191
    int b = i >> 10, o = i & 1023;
    float m = -INFINITY;
    for (int c = 0; c < GCH; ++c) m = fmaxf(m, gp[((size_t)c * BB + b) * 1024 + o]);
    g[(size_t)b * 1024 + o] = m;
}

// one wave per (b,t): H1[b][t] = m0b[t] + dot(G[b], m0w[:,t])   (1024 waves)
__global__ __launch_bounds__(256) void mlp1_kernel(
        const float* __restrict__ g, const float* __restrict__ m0w,
        const float* __restrict__ m0b, float* __restrict__ H1) {
    int wid = blockIdx.x * 4 + (threadIdx.x >> 6);
    int lane = threadIdx.x & 63;
    int b = wid >> 7, t = wid & 127;
    float s = 0.f;
    for (int f = lane; f < 1024; f += 64)
        s += g[(size_t)b * 1024 + f] * m0w[(size_t)f * 128 + t];
#pragma unroll
    for (int off = 32; off > 0; off >>= 1) s += __shfl_down(s, off);
    if (lane == 0) H1[(size_t)b * 128 + t] = s + m0b[t];
}

// one wave per (b,t): H2[b][t] = m1b[t] + dot(H1[b], m1w[:,t])   (512 waves)
__global__ __launch_bounds__(256) void mlp2_kernel(
        const float* __restrict__ H1, const float* __restrict__ m1w,
        const float* __restrict__ m1b, float* __restrict__ H2) {
    int wid = blockIdx.x * 4 + (threadIdx.x >> 6);
    int lane = threadIdx.x & 63;
    int b = wid >> 6, t = wid & 63;
    float s = 0.f;
    for (int f = lane; f < 128; f += 64)
        s += H1[(size_t)b * 128 + f] * m1w[(size_t)f * 64 + t];
#pragma unroll
    for (int off = 32; off > 0; off >>= 1) s += __shfl_down(s, off);
    if (lane == 0) H2[(size_t)b * 64 + t] = s + m1b[t];
}

// one wave per b: out[b] = m2b[0] + dot(H2[b], m2w)   (8 waves)
__global__ __launch_bounds__(256) void mlp3_kernel(
        const float* __restrict__ H2, const float* __restrict__ m2w,
        const float* __restrict__ m2b, float* __restrict__ out) {
    int b = blockIdx.x * 4 + (threadIdx.x >> 6);
    int lane = threadIdx.x & 63;
    if (b >= BB) return;
    float s = H2[(size_t)b * 64 + lane] * m2w[lane];
#pragma unroll
    for (int off = 32; off > 0; off >>= 1) s += __shfl_down(s, off);
    if (lane == 0) out[b] = s + m2b[0];
}

// ---------------------------------------------------------------------------
extern "C" void kernel_launch(void* const* d_in, const int* in_sizes, int n_in,
                              void* d_out, int out_size, void* d_ws, size_t ws_size,
                              hipStream_t stream) {
    const float* x0 = (const float*)d_in[0];
    const float* w[5], * bi[5];
    for (int i = 0; i < 5; ++i) { w[i] = (const float*)d_in[1 + 2 * i]; bi[i] = (const float*)d_in[2 + 2 * i]; }
    const float* m0w = (const float*)d_in[11]; const float* m0b = (const float*)d_in[12];
    const float* m1w = (const float*)d_in[13]; const float* m1b = (const float*)d_in[14];
    const float* m2w = (const float*)d_in[15]; const float* m2b = (const float*)d_in[16];

    const int fouts[5] = {64, 128, 256, 512, 1024};
    const int shifts[5] = {6, 7, 8, 9, 10};
    const int woff[5] = {0, 8192, 40960, 172032, 696320};
    const size_t WTALL = 2793472;   // shorts

    float* X0 = (float*)d_ws;
    float* X1 = X0 + (size_t)BN * 1024;
    float* T  = X1 + (size_t)BN * 1024;
    float* SQ = T  + (size_t)BN * 1024;
    int*   IDX = (int*)(SQ + BN);
    unsigned short* XSh = (unsigned short*)(IDX + (size_t)BN * KK);
    unsigned short* XSl = XSh + (size_t)BN * 512;
    unsigned short* WTall = XSl + (size_t)BN * 512;
    float* GP = (float*)(WTall + WTALL);
    float* G  = GP + (size_t)GCH * BB * 1024;
    float* H1 = G + (size_t)BB * 1024;
    float* H2 = H1 + (size_t)BB * 128;
    float* bufs[2] = {X0, X1};
    float2* CAND = (float2*)T;        // 21 MB, consumed by merge before gemm
                                      // overwrites T (Tout)

    xsplit3_kernel<<<(BN + 255) / 256, 256, 0, stream>>>(x0, XSh, XSl, SQ);
    wsplit_all_kernel<<<(1396736 + 255) / 256, 256, 0, stream>>>(w[0], w[1], w[2], w[3], w[4], WTall);

    int fin = 3;
    for (int l = 0; l < 5; ++l) {
        int fout = fouts[l];
        float* nxt = bufs[l & 1];
        int Fg = (l == 0) ? 32 : fin;      // padded K for MFMA path

        // gram + fused per-tile top-K (no d2 materialization)
        dim3 gg2(136, BB);   // upper-triangle 128x128 tile pairs
        knn_gram_kernel<<<gg2, 256, 0, stream>>>(XSh, XSl, SQ, CAND, Fg);
        knn_merge_kernel<<<BN / 4, 256, 0, stream>>>(CAND, IDX);

        if (l == 3) {
            // 256^2-tile pipelined GEMM (K' = 3*fin via K-concat); grid 256
            // blocks = 1/CU (measured best at l3; l2 would half-fill CUs,
            // l4 measured faster on 128^2: 113 vs 120 us).
            int nby = (2 * fout) / 256;
            gemm2_8ph_kernel<<<dim3(64 * nby), 512, 0, stream>>>(
                XSh, XSl, WTall + woff[l], bi[l], nxt, T, fin, fout, nby);
        } else {
            dim3 gg(BN / 128, (2 * fout) / 128);
            gemm2_mfma_kernel<<<gg, 256, 0, stream>>>(XSh, XSl, WTall + woff[l], bi[l], nxt, T, Fg, fout);
        }

        if (l < 4) {
            dim3 gmg(NN / 4, BB);
            gathermax_fused_kernel<<<gmg, 256, 0, stream>>>(nxt, T, IDX, XSh, XSl, SQ, shifts[l]);
        } else {
            dim3 gmg(GCH, BB);
            gathermax_gmax_kernel<<<gmg, 256, 0, stream>>>(nxt, T, IDX, GP);
        }

        fin = fout;
    }

    gmax2_kernel<<<32, 256, 0, stream>>>(GP, G);
    mlp1_kernel<<<256, 256, 0, stream>>>(G, m0w, m0b, H1);
    mlp2_kernel<<<128, 256, 0, stream>>>(H1, m1w, m1b, H2);
    mlp3_kernel<<<2, 256, 0, stream>>>(H2, m2w, m2b, (float*)d_out);
}

// Round 7
// 1027.528 us; speedup vs baseline: 1.2896x; 1.2896x over previous
//
#include <hip/hip_runtime.h>
#include <hip/hip_bf16.h>
#include <math.h>

#define BB 8
#define NN 2048
#define KK 10
#define BN (BB * NN)
#define HC 1024            // cols per d2 half (2 halves = full 2048)
#define GCH 64             // point-chunks for fused l4 gathermax+gmax

typedef __attribute__((ext_vector_type(8))) short bf16x8;
typedef __attribute__((ext_vector_type(4))) float f32x4;

__device__ inline unsigned short f2bf(float f) {
    unsigned int u = __float_as_uint(f);
    unsigned int r = u + 0x7fffu + ((u >> 16) & 1u);
    return (unsigned short)(r >> 16);
}
__device__ inline float bf2f(unsigned short h) {
    return __uint_as_float((unsigned int)h << 16);
}

// async global->LDS DMA, 16 B/lane, dest = wave-uniform base + lane*16 [m97]
__device__ __forceinline__ void async16(const void* g, void* l) {
    __builtin_amdgcn_global_load_lds(
        (const __attribute__((address_space(1))) void*)g,
        (__attribute__((address_space(3))) void*)l, 16, 0, 0);
}

// ---------------------------------------------------------------------------
// Layer 0: split x (F=3) into hi/lo bf16 padded to 32, plus row sq-norms.
__global__ void xsplit3_kernel(const float* __restrict__ x,
                               unsigned short* __restrict__ hi,
                               unsigned short* __restrict__ lo,
                               float* __restrict__ sq) {
    int row = blockIdx.x * blockDim.x + threadIdx.x;
    if (row >= BN) return;
    unsigned short hbuf[32], lbuf[32];
#pragma unroll
    for (int f = 0; f < 32; ++f) { hbuf[f] = 0; lbuf[f] = 0; }
    float s = 0.f;
#pragma unroll
    for (int f = 0; f < 3; ++f) {
        float v = x[(size_t)row * 3 + f];
        s += v * v;
        unsigned short h = f2bf(v);
        hbuf[f] = h;
        lbuf[f] = f2bf(v - bf2f(h));
    }
    sq[row] = s;
#pragma unroll
    for (int f = 0; f < 32; f += 8) {
        *(uint4*)&hi[(size_t)row * 32 + f] = *(uint4*)&hbuf[f];
        *(uint4*)&lo[(size_t)row * 32 + f] = *(uint4*)&lbuf[f];
    }
}

// ---------------------------------------------------------------------------
// All 5 layers' WT built in ONE launch (weights are layer-static).
__global__ void wsplit_all_kernel(const float* __restrict__ w0, const float* __restrict__ w1,
                                  const float* __restrict__ w2, const float* __restrict__ w3,
                                  const float* __restrict__ w4, unsigned short* __restrict__ WTall) {
    const int fins[5]  = {3, 64, 128, 256, 512};
    const int fpads[5] = {32, 64, 128, 256, 512};
    const int fouts[5] = {64, 128, 256, 512, 1024};
    const int eoff[6]  = {0, 4096, 20480, 86016, 348160, 1396736};
    const int woff[5]  = {0, 8192, 40960, 172032, 696320};
    int i = blockIdx.x * blockDim.x + threadIdx.x;
    if (i >= 1396736) return;
    int l;
    if (i < eoff[1]) l = 0; else if (i < eoff[2]) l = 1;
    else if (i < eoff[3]) l = 2; else if (i < eoff[4]) l = 3; else l = 4;
    int e = i - eoff[l];
    const float* w = (l == 0) ? w0 : (l == 1) ? w1 : (l == 2) ? w2 : (l == 3) ? w3 : w4;
    int fin = fins[l], fpad = fpads[l], fout = fouts[l];
    unsigned short* WT = WTall + woff[l];
    int op = e % (2 * fout);
    int f = e / (2 * fout);
    float v = 0.f;
    if (f < fin) {
        if (op < fout) v = w[(size_t)f * fout + op] - w[(size_t)(fin + f) * fout + op];
        else v = w[(size_t)(fin + f) * fout + (op - fout)];
    }
    unsigned short h = f2bf(v);
    unsigned short lo = f2bf(v - bf2f(h));
    WT[(size_t)op * (2 * fpad) + f] = h;
    WT[(size_t)op * (2 * fpad) + fpad + f] = lo;
}

// ---------------------------------------------------------------------------
// kNN Gram GEMM (validated round 18/20, verbatim): SYMMETRIC upper-triangle
// tiles, mirror via 64x129 LDS transpose; bf16 hi/lo 3-phase MFMA; async16;
// XOR swizzle.
__global__ __launch_bounds__(256) void knn_gram_kernel(
        const unsigned short* __restrict__ xh, const unsigned short* __restrict__ xl,
        const float* __restrict__ sq, float* __restrict__ d2a,
        float* __restrict__ d2b, int F) {
    int b = blockIdx.y;
    int t = blockIdx.x, ti = 0;
    while (t >= 16 - ti) { t -= 16 - ti; ti++; }
    int tj = ti + t;
    int row0 = ti * 128;
    int col0 = tj * 128;
    const unsigned short* xhb = xh + (size_t)b * NN * F;
    const unsigned short* xlb = xl + (size_t)b * NN * F;
    const float* sqb = sq + (size_t)b * NN;

    __shared__ __align__(16) unsigned char smem_raw[33024];
    unsigned short* Ah = (unsigned short*)smem_raw;
    unsigned short* Al = Ah + 128 * 32;
    unsigned short* Bh = Al + 128 * 32;
    unsigned short* Bl = Bh + 128 * 32;
    float* LT = (float*)smem_raw;

    int tid = threadIdx.x;
    int lane = tid & 63;
    int wave = tid >> 6;
    int wr = (wave >> 1) * 64, wc = (wave & 1) * 64;
    int l15 = lane & 15, kq = lane >> 4;
    int rsub = lane >> 2;
    int csub = (((lane & 3) ^ ((lane >> 3) & 3))) * 8;
    int kqs = (kq ^ ((l15 >> 1) & 3)) * 8;

    f32x4 acc[4][4];
#pragma unroll
    for (int mt = 0; mt < 4; ++mt)
#pragma unroll
        for (int nt = 0; nt < 4; ++nt) acc[mt][nt] = (f32x4){0.f, 0.f, 0.f, 0.f};

    for (int kc = 0; kc < F; kc += 32) {
        __syncthreads();
#pragma unroll
        for (int j = 0; j < 2; ++j) {
            int row = wave * 32 + j * 16 + rsub;
            int dsto = wave * 1024 + j * 512;
            async16(xhb + (size_t)(row0 + row) * F + kc + csub, Ah + dsto);
            async16(xlb + (size_t)(row0 + row) * F + kc + csub, Al + dsto);
            async16(xhb + (size_t)(col0 + row) * F + kc + csub, Bh + dsto);
            async16(xlb + (size_t)(col0 + row) * F + kc + csub, Bl + dsto);
        }
        __syncthreads();
        bf16x8 bh[4], bl[4];
#pragma unroll
        for (int t4 = 0; t4 < 4; ++t4) {
            bh[t4] = *(const bf16x8*)&Bh[(wc + t4 * 16 + l15) * 32 + kqs];
            bl[t4] = *(const bf16x8*)&Bl[(wc + t4 * 16 + l15) * 32 + kqs];
        }
#pragma unroll
        for (int mt = 0; mt < 4; ++mt) {
            bf16x8 ah = *(const bf16x8*)&Ah[(wr + mt * 16 + l15) * 32 + kqs];
            bf16x8 al = *(const bf16x8*)&Al[(wr + mt * 16 + l15) * 32 + kqs];
#pragma unroll
            for (int nt = 0; nt < 4; ++nt) {
                acc[mt][nt] = __builtin_amdgcn_mfma_f32_16x16x32_bf16(ah, bh[nt], acc[mt][nt], 0, 0, 0);
                acc[mt][nt] = __builtin_amdgcn_mfma_f32_16x16x32_bf16(al, bh[nt], acc[mt][nt], 0, 0, 0);
                acc[mt][nt] = __builtin_amdgcn_mfma_f32_16x16x32_bf16(ah, bl[nt], acc[mt][nt], 0, 0, 0);
            }
        }
    }
    {
        float* dst = (col0 < HC) ? d2a : d2b;
        int lc0 = col0 & (HC - 1);
#pragma unroll
        for (int mt = 0; mt < 4; ++mt) {
            int rbase = row0 + wr + mt * 16 + kq * 4;
#pragma unroll
            for (int nt = 0; nt < 4; ++nt) {
                int cc = wc + nt * 16 + l15;
                float sqc = sqb[col0 + cc];
#pragma unroll
                for (int r = 0; r < 4; ++r) {
                    float v = (sqb[rbase + r] + sqc) - 2.f * acc[mt][nt][r];
                    acc[mt][nt][r] = v;
                    dst[((size_t)b * NN + rbase + r) * HC + lc0 + cc] = v;
                }
            }
        }
    }
    if (ti != tj) {
        float* mdst = (row0 < HC) ? d2a : d2b;
        int mc0 = row0 & (HC - 1);
#pragma unroll
        for (int h = 0; h < 2; ++h) {
            __syncthreads();
            if ((wave & 1) == h) {
#pragma unroll
                for (int mt = 0; mt < 4; ++mt)
#pragma unroll
                    for (int nt = 0; nt < 4; ++nt)
#pragma unroll
                        for (int r = 0; r < 4; ++r)
                            LT[(nt * 16 + l15) * 129 + (wr + mt * 16 + kq * 4 + r)] =
                                acc[mt][nt][r];
            }
            __syncthreads();
#pragma unroll
            for (int it = 0; it < 8; ++it) {
                int v = tid + it * 256;
                int lr = v >> 5, c4 = v & 31;
                float4 val;
                val.x = LT[lr * 129 + c4 * 4];
                val.y = LT[lr * 129 + c4 * 4 + 1];
                val.z = LT[lr * 129 + c4 * 4 + 2];
                val.w = LT[lr * 129 + c4 * 4 + 3];
                *(float4*)&mdst[((size_t)b * NN + col0 + h * 64 + lr) * HC + mc0 + c4 * 4] = val;
            }
        }
    }
}

// ---------------------------------------------------------------------------
// kNN selection (validated round 15): WAVE-PER-ROW, no LDS, no barriers.
__global__ __launch_bounds__(256) void knn_select_kernel(
        const float* __restrict__ d2a, const float* __restrict__ d2b,
        int* __restrict__ idx) {
    int row = blockIdx.x * 4 + (threadIdx.x >> 6);
    int lane = threadIdx.x & 63;
    const float* ra = d2a + (size_t)row * HC;
    const float* rb = d2b + (size_t)row * HC;

    float4 v[8];
#pragma unroll
    for (int it = 0; it < 4; ++it) {
        v[it]     = *(const float4*)&ra[it * 256 + lane * 4];
        v[it + 4] = *(const float4*)&rb[it * 256 + lane * 4];
    }

    float bestd[KK];
    int besti[KK];
#pragma unroll
    for (int k = 0; k < KK; ++k) { bestd[k] = INFINITY; besti[k] = 0x7fffffff; }

#pragma unroll
    for (int it = 0; it < 8; ++it) {
        int cbase = ((it < 4) ? (it * 256) : (HC + (it - 4) * 256)) + lane * 4;
        float dv[4] = {v[it].x, v[it].y, v[it].z, v[it].w};
#pragma unroll
        for (int s4 = 0; s4 < 4; ++s4) {
            float d = dv[s4];
            if (d < bestd[KK - 1]) {
                bestd[KK - 1] = d;
                besti[KK - 1] = cbase + s4;
#pragma unroll
                for (int s = KK - 1; s > 0; --s) {
                    if (bestd[s] < bestd[s - 1]) {
                        float td = bestd[s]; bestd[s] = bestd[s - 1]; bestd[s - 1] = td;
                        int ti = besti[s]; besti[s] = besti[s - 1]; besti[s - 1] = ti;
                    }
                }
            }
        }
    }

    int h = 0;
    int mywin = 0;
    for (int s = 0; s < KK; ++s) {
        float dd = (h < KK) ? bestd[h] : INFINITY;
        int ii = (h < KK) ? besti[h] : 0x7fffffff;
        float d0 = dd; int i0 = ii;
#pragma unroll
        for (int off = 32; off > 0; off >>= 1) {
            float od = __shfl_xor(dd, off);
            int oi = __shfl_xor(ii, off);
            if (od < dd || (od == dd && oi < ii)) { dd = od; ii = oi; }
        }
        if (lane == s) mywin = ii;
        if (h < KK && i0 == ii && d0 == dd) h++;
    }
    if (lane < KK) idx[(size_t)row * KK + lane] = mywin;
}

// ---------------------------------------------------------------------------
// MFMA GEMM (validated rounds 16/17/20, verbatim): single-pass 4-tile staging
// + XOR swizzle. LDS 32 KB. Used for layers 0,1,2,4 (full-GPU 128^2 grids).
__global__ __launch_bounds__(256) void gemm2_mfma_kernel(
        const unsigned short* __restrict__ XSh, const unsigned short* __restrict__ XSl,
        const unsigned short* __restrict__ WT, const float* __restrict__ bias,
        float* __restrict__ Aout, float* __restrict__ Tout, int fin, int fout) {
    int m0 = blockIdx.x * 128;
    int n0 = blockIdx.y * 128;
    __shared__ __align__(16) unsigned short AsB[4 * 128 * 32];   // 32 KB
    unsigned short* Ah = AsB;
    unsigned short* Al = Ah + 128 * 32;
    unsigned short* Bh = Al + 128 * 32;
    unsigned short* Bl = Bh + 128 * 32;

    int tid = threadIdx.x;
    int lane = tid & 63;
    int wave = tid >> 6;
    int wr = (wave >> 1) * 64, wc = (wave & 1) * 64;
    int l15 = lane & 15, kq = lane >> 4;
    int rsub = lane >> 2;
    int csub = (((lane & 3) ^ ((lane >> 3) & 3))) * 8;
    int kqs = (kq ^ ((l15 >> 1) & 3)) * 8;
    int w2f = 2 * fin;

    f32x4 acc[4][4];
#pragma unroll
    for (int mt = 0; mt < 4; ++mt)
#pragma unroll
        for (int nt = 0; nt < 4; ++nt) acc[mt][nt] = (f32x4){0.f, 0.f, 0.f, 0.f};

    for (int kc = 0; kc < fin; kc += 32) {
        __syncthreads();
#pragma unroll
        for (int j = 0; j < 2; ++j) {
            int row = wave * 32 + j * 16 + rsub;
            int dsto = wave * 1024 + j * 512;
            async16(XSh + (size_t)(m0 + row) * fin + kc + csub, Ah + dsto);
            async16(XSl + (size_t)(m0 + row) * fin + kc + csub, Al + dsto);
            async16(WT + (size_t)(n0 + row) * w2f + kc + csub, Bh + dsto);
            async16(WT + (size_t)(n0 + row) * w2f + fin + kc + csub, Bl + dsto);
        }
        __syncthreads();
        bf16x8 bh[4], bl[4];
#pragma unroll
        for (int t = 0; t < 4; ++t) {
            bh[t] = *(const bf16x8*)&Bh[(wc + t * 16 + l15) * 32 + kqs];
            bl[t] = *(const bf16x8*)&Bl[(wc + t * 16 + l15) * 32 + kqs];
        }
#pragma unroll
        for (int mt = 0; mt < 4; ++mt) {
            bf16x8 ah = *(const bf16x8*)&Ah[(wr + mt * 16 + l15) * 32 + kqs];
            bf16x8 al = *(const bf16x8*)&Al[(wr + mt * 16 + l15) * 32 + kqs];
#pragma unroll
            for (int nt = 0; nt < 4; ++nt) {
                acc[mt][nt] = __builtin_amdgcn_mfma_f32_16x16x32_bf16(ah, bh[nt], acc[mt][nt], 0, 0, 0);
                acc[mt][nt] = __builtin_amdgcn_mfma_f32_16x16x32_bf16(al, bh[nt], acc[mt][nt], 0, 0, 0);
                acc[mt][nt] = __builtin_amdgcn_mfma_f32_16x16x32_bf16(ah, bl[nt], acc[mt][nt], 0, 0, 0);
            }
        }
    }
#pragma unroll
    for (int mt = 0; mt < 4; ++mt) {
        int mbase = m0 + wr + mt * 16 + kq * 4;
#pragma unroll
        for (int nt = 0; nt < 4; ++nt) {
            int oc = n0 + wc + nt * 16 + l15;
            f32x4 c = acc[mt][nt];
            if (oc < fout) {
                float bv = bias[oc];
#pragma unroll
                for (int r = 0; r < 4; ++r)
                    Aout[(size_t)(mbase + r) * fout + oc] = c[r] + bv;
            } else {
                int o2 = oc - fout;
#pragma unroll
                for (int r = 0; r < 4; ++r)
                    Tout[(size_t)(mbase + r) * fout + o2] = c[r];
            }
        }
    }
}

// ---------------------------------------------------------------------------
// 256^2-tile 8-phase pipelined GEMM (round-1 verbatim, refcheck'd) — layer 3
// only (grid 256 = 1 block/CU; measured best at l3 in R5: total -47 us).
__device__ __forceinline__ const unsigned short* tbaseA(
        const unsigned short* XSh, const unsigned short* XSl, int F, int t) {
    int ko = t * 64;
    if (ko < F) return XSh + ko;
    if (ko < 2 * F) return XSl + (ko - F);
    return XSh + (ko - 2 * F);
}
__device__ __forceinline__ const unsigned short* tbaseB(
        const unsigned short* WT, int F, int t) {
    int ko = t * 64;
    if (ko < F) return WT + ko;
    if (ko < 2 * F) return WT + (ko - F);       // hi again
    return WT + F + (ko - 2 * F);               // lo half of the row
}

#define GBAR() asm volatile("s_barrier" ::: "memory")

__global__ __launch_bounds__(512, 2) void gemm2_8ph_kernel(
        const unsigned short* __restrict__ XSh, const unsigned short* __restrict__ XSl,
        const unsigned short* __restrict__ WT, const float* __restrict__ bias,
        float* __restrict__ Aout, float* __restrict__ Tout, int F, int fout, int nby) {
    __shared__ __align__(16) unsigned short Lds[65536];   // 128 KiB

    int nwg = gridDim.x;
    int bid = blockIdx.x;
    int q = nwg >> 3;
    int swz = (bid & 7) * q + (bid >> 3);
    int by = swz % nby;
    int bx = swz / nby;
    int m0 = bx * 256, n0 = by * 256;

    int tid = threadIdx.x;
    int lane = tid & 63;
    int wave = tid >> 6;
    int mw = wave >> 2;
    int nw = wave & 3;
    int l15 = lane & 15, kq = lane >> 4;
    int rx7 = l15 & 7;

    int isA = (wave < 4);
    size_t rowmul = isA ? (size_t)F : (size_t)(2 * F);
    int orgn = isA ? m0 : n0;
    int r8 = lane >> 3;
    int cb8 = ((lane & 7) ^ r8) * 8;
    int subb = (wave & 3) * 8;
    int ldsoA = isA ? 0 : 16384;

    int nt = (3 * F) >> 6;

    f32x4 acc[8][4];
#pragma unroll
    for (int mt = 0; mt < 8; ++mt)
#pragma unroll
        for (int nn = 0; nn < 4; ++nn) acc[mt][nn] = (f32x4){0.f, 0.f, 0.f, 0.f};

    auto stage = [&](const unsigned short* tb, int par, int j) {
        int sub = subb + j;
        async16(tb + (size_t)(orgn + sub * 8 + r8) * rowmul + cb8,
                Lds + par * 32768 + ldsoA + sub * 512);
    };

    {
        const unsigned short* t0 = isA ? tbaseA(XSh, XSl, F, 0) : tbaseB(WT, F, 0);
        const unsigned short* t1 = isA ? tbaseA(XSh, XSl, F, 1) : tbaseB(WT, F, 1);
#pragma unroll
        for (int j = 0; j < 8; ++j) stage(t0, 0, j);
#pragma unroll
        for (int j = 0; j < 4; ++j) stage(t1, 1, j);
    }
    asm volatile("s_waitcnt vmcnt(4)" ::: "memory");
    GBAR();

    for (int t = 0; t < nt; ++t) {
        const unsigned short* Ab = Lds + (t & 1) * 32768;
        const unsigned short* Bb = Ab + 16384;
        bool s1 = (t + 1 < nt), s2 = (t + 2 < nt);
        const unsigned short* tb1 = s1 ? (isA ? tbaseA(XSh, XSl, F, t + 1)
                                              : tbaseB(WT, F, t + 1)) : XSh;
        const unsigned short* tb2 = s2 ? (isA ? tbaseA(XSh, XSl, F, t + 2)
                                              : tbaseB(WT, F, t + 2)) : XSh;
        int p1 = (t + 1) & 1, p0 = t & 1;

        bf16x8 aF[4][2], bA[2][2], bB[2][2];

#pragma unroll
        for (int mt = 0; mt < 4; ++mt)
#pragma unroll
            for (int kf = 0; kf < 2; ++kf)
                aF[mt][kf] = *(const bf16x8*)&Ab[(mw * 128 + mt * 16 + l15) * 64 +
                                                 ((kf * 4 + kq) ^ rx7) * 8];
#pragma unroll
        for (int nn = 0; nn < 2; ++nn)
#pragma unroll
            for (int kf = 0; kf < 2; ++kf)
                bA[nn][kf] = *(const bf16x8*)&Bb[(nw * 64 + nn * 16 + l15) * 64 +
                                                 ((kf * 4 + kq) ^ rx7) * 8];
        if (s1) { stage(tb1, p1, 4); stage(tb1, p1, 5); }
        GBAR();
        __builtin_amdgcn_s_setprio(1);
#pragma unroll
        for (int mt = 0; mt < 4; ++mt)
#pragma unroll
            for (int nn = 0; nn < 2; ++nn) {
                acc[mt][nn] = __builtin_amdgcn_mfma_f32_16x16x32_bf16(aF[mt][0], bA[nn][0], acc[mt][nn], 0, 0, 0);
                acc[mt][nn] = __builtin_amdgcn_mfma_f32_16x16x32_bf16(aF[mt][1], bA[nn][1], acc[mt][nn], 0, 0, 0);
            }
        __builtin_amdgcn_s_setprio(0);
        GBAR();

#pragma unroll
        for (int nn = 0; nn < 2; ++nn)
#pragma unroll
            for (int kf = 0; kf < 2; ++kf)
                bB[nn][kf] = *(const bf16x8*)&Bb[(nw * 64 + (nn + 2) * 16 + l15) * 64 +
                                                 ((kf * 4 + kq) ^ rx7) * 8];
        if (s1) { stage(tb1, p1, 6); stage(tb1, p1, 7); }
        GBAR();
        __builtin_amdgcn_s_setprio(1);
#pragma unroll
        for (int mt = 0; mt < 4; ++mt)
#pragma unroll
            for (int nn = 0; nn < 2; ++nn) {
                acc[mt][nn + 2] = __builtin_amdgcn_mfma_f32_16x16x32_bf16(aF[mt][0], bB[nn][0], acc[mt][nn + 2], 0, 0, 0);
                acc[mt][nn + 2] = __builtin_amdgcn_mfma_f32_16x16x32_bf16(aF[mt][1], bB[nn][1], acc[mt][nn + 2], 0, 0, 0);
            }
        __builtin_amdgcn_s_setprio(0);
        GBAR();

#pragma unroll
        for (int mt = 0; mt < 4; ++mt)
#pragma unroll
            for (int kf = 0; kf < 2; ++kf)
                aF[mt][kf] = *(const bf16x8*)&Ab[(mw * 128 + (mt + 4) * 16 + l15) * 64 +
                                                 ((kf * 4 + kq) ^ rx7) * 8];
        GBAR();
        __builtin_amdgcn_s_setprio(1);
#pragma unroll
        for (int mt = 0; mt < 4; ++mt)
#pragma unroll
            for (int nn = 0; nn < 2; ++nn) {
                acc[mt + 4][nn] = __builtin_amdgcn_mfma_f32_16x16x32_bf16(aF[mt][0], bA[nn][0], acc[mt + 4][nn], 0, 0, 0);
                acc[mt + 4][nn] = __builtin_amdgcn_mfma_f32_16x16x32_bf16(aF[mt][1], bA[nn][1], acc[mt + 4][nn], 0, 0, 0);
            }
        __builtin_amdgcn_s_setprio(0);
        GBAR();

        if (s2) { stage(tb2, p0, 0); stage(tb2, p0, 1); stage(tb2, p0, 2); stage(tb2, p0, 3); }
        GBAR();
        __builtin_amdgcn_s_setprio(1);
#pragma unroll
        for (int mt = 0; mt < 4; ++mt)
#pragma unroll
            for (int nn = 0; nn < 2; ++nn) {
                acc[mt + 4][nn + 2] = __builtin_amdgcn_mfma_f32_16x16x32_bf16(aF[mt][0], bB[nn][0], acc[mt + 4][nn + 2], 0, 0, 0);
                acc[mt + 4][nn + 2] = __builtin_amdgcn_mfma_f32_16x16x32_bf16(aF[mt][1], bB[nn][1], acc[mt + 4][nn + 2], 0, 0, 0);
            }
        __builtin_amdgcn_s_setprio(0);
        if (s2)      asm volatile("s_waitcnt vmcnt(4)" ::: "memory");
        else if (s1) asm volatile("s_waitcnt vmcnt(0)" ::: "memory");
        GBAR();
    }

#pragma unroll
    for (int mt = 0; mt < 8; ++mt) {
        int mbase = m0 + mw * 128 + mt * 16 + kq * 4;
#pragma unroll
        for (int nn = 0; nn < 4; ++nn) {
            int oc = n0 + nw * 64 + nn * 16 + l15;
            f32x4 c = acc[mt][nn];
            if (oc < fout) {
                float bv = bias[oc];
#pragma unroll
                for (int r = 0; r < 4; ++r)
                    Aout[(size_t)(mbase + r) * fout + oc] = c[r] + bv;
            } else {
                int o2 = oc - fout;
#pragma unroll
                for (int r = 0; r < 4; ++r)
                    Tout[(size_t)(mbase + r) * fout + o2] = c[r];
            }
        }
    }
}

// ---------------------------------------------------------------------------
// FUSED gathermax (layers 0-3): wave-per-row; writes bf16 splits + sq only.
__global__ __launch_bounds__(256) void gathermax_fused_kernel(
        const float* __restrict__ A, const float* __restrict__ T,
        const int* __restrict__ idx, unsigned short* __restrict__ hi,
        unsigned short* __restrict__ lo, float* __restrict__ sq, int shift) {
    int b = blockIdx.y;
    int wave = threadIdx.x >> 6;
    int lane = threadIdx.x & 63;
    int pnl = blockIdx.x * 4 + wave;
    int pn = (b << 11) + pnl;
    int fout = 1 << shift;
    int nf4 = fout >> 2;
    const float* Tb = T + ((size_t)b << 11) * fout;
    const int* ip = idx + (size_t)pn * KK;
    int j[KK];
#pragma unroll
    for (int k = 0; k < KK; ++k) j[k] = ip[k];

    float s = 0.f;
    for (int f4 = lane; f4 < nf4; f4 += 64) {
        int o = f4 * 4;
        float4 m = {-INFINITY, -INFINITY, -INFINITY, -INFINITY};
#pragma unroll
        for (int k = 0; k < KK; ++k) {
            float4 t = *(const float4*)&Tb[(size_t)j[k] * fout + o];
            m.x = fmaxf(m.x, t.x); m.y = fmaxf(m.y, t.y);
            m.z = fmaxf(m.z, t.z); m.w = fmaxf(m.w, t.w);
        }
        float4 a = *(const float4*)&A[(size_t)pn * fout + o];
        float h4[4];
        h4[0] = a.x + m.x; h4[1] = a.y + m.y; h4[2] = a.z + m.z; h4[3] = a.w + m.w;
        uint2 uh, ul;
        unsigned short hs[4], ls[4];
#pragma unroll
        for (int q = 0; q < 4; ++q) {
            float h = h4[q] > 0.f ? h4[q] : 0.2f * h4[q];
            s += h * h;
            unsigned short hh = f2bf(h);
            hs[q] = hh;
            ls[q] = f2bf(h - bf2f(hh));
        }
        uh.x = (unsigned)hs[0] | ((unsigned)hs[1] << 16);
        uh.y = (unsigned)hs[2] | ((unsigned)hs[3] << 16);
        ul.x = (unsigned)ls[0] | ((unsigned)ls[1] << 16);
        ul.y = (unsigned)ls[2] | ((unsigned)ls[3] << 16);
        *(uint2*)&hi[(size_t)pn * fout + o] = uh;
        *(uint2*)&lo[(size_t)pn * fout + o] = ul;
    }
#pragma unroll
    for (int off = 32; off > 0; off >>= 1) s += __shfl_down(s, off);
    if (lane == 0) sq[pn] = s;
}

// ---------------------------------------------------------------------------
// FUSED l4 gathermax + gmax pass 1 (validated round 20).
__global__ __launch_bounds__(256) void gathermax_gmax_kernel(
        const float* __restrict__ A, const float* __restrict__ T,
        const int* __restrict__ idx, float* __restrict__ gp) {
    int chunk = blockIdx.x;
    int b = blockIdx.y;
    int o = threadIdx.x * 4;
    const float* Tb = T + ((size_t)b << 11) * 1024;
    float4 gm = {-INFINITY, -INFINITY, -INFINITY, -INFINITY};
    for (int p = 0; p < NN / GCH; ++p) {
        int pnl = chunk * (NN / GCH) + p;
        int pn = (b << 11) + pnl;
        const int* ip = idx + (size_t)pn * KK;
        float4 m = {-INFINITY, -INFINITY, -INFINITY, -INFINITY};
#pragma unroll
        for (int k = 0; k < KK; ++k) {
            int j = ip[k];
            float4 t = *(const float4*)&Tb[(size_t)j * 1024 + o];
            m.x = fmaxf(m.x, t.x); m.y = fmaxf(m.y, t.y);
            m.z = fmaxf(m.z, t.z); m.w = fmaxf(m.w, t.w);
        }
        float4 a = *(const float4*)&A[(size_t)pn * 1024 + o];
        float4 h;
        h.x = a.x + m.x; h.y = a.y + m.y; h.z = a.z + m.z; h.w = a.w + m.w;
        h.x = h.x > 0.f ? h.x : 0.2f * h.x;
        h.y = h.y > 0.f ? h.y : 0.2f * h.y;
        h.z = h.z > 0.f ? h.z : 0.2f * h.z;
        h.w = h.w > 0.f ? h.w : 0.2f * h.w;
        gm.x = fmaxf(gm.x, h.x); gm.y = fmaxf(gm.y, h.y);
        gm.z = fmaxf(gm.z, h.z); gm.w = fmaxf(gm.w, h.w);
    }
    *(float4*)&gp[((size_t)chunk * BB + b) * 1024 + o] = gm;
}

// ---------------------------------------------------------------------------
// Parallel tail: gmax2 (coalesced) then wave-per-output MLP stages.
__global__ void gmax2_kernel(const float* __restrict__ gp, float* __restrict__ g) {
    int i = blockIdx.x * 256 + threadIdx.x;      // 0..8191
    int b = i >> 10, o = i & 1023;
    float m = -INFINITY;
    for (int c = 0; c < GCH; ++c) m = fmaxf(m, gp[((size_t)c * BB + b) * 1024 + o]);
    g[(size_t)b * 1024 + o] = m;
}

// one wave per (b,t): H1[b][t] = m0b[t] + dot(G[b], m0w[:,t])   (1024 waves)
__global__ __launch_bounds__(256) void mlp1_kernel(
        const float* __restrict__ g, const float* __restrict__ m0w,
        const float* __restrict__ m0b, float* __restrict__ H1) {
    int wid = blockIdx.x * 4 + (threadIdx.x >> 6);
    int lane = threadIdx.x & 63;
    int b = wid >> 7, t = wid & 127;
    float s = 0.f;
    for (int f = lane; f < 1024; f += 64)
        s += g[(size_t)b * 1024 + f] * m0w[(size_t)f * 128 + t];
#pragma unroll
    for (int off = 32; off > 0; off >>= 1) s += __shfl_down(s, off);
    if (lane == 0) H1[(size_t)b * 128 + t] = s + m0b[t];
}

// one wave per (b,t): H2[b][t] = m1b[t] + dot(H1[b], m1w[:,t])   (512 waves)
__global__ __launch_bounds__(256) void mlp2_kernel(
        const float* __restrict__ H1, const float* __restrict__ m1w,
        const float* __restrict__ m1b, float* __restrict__ H2) {
    int wid = blockIdx.x * 4 + (threadIdx.x >> 6);
    int lane = threadIdx.x & 63;
    int b = wid >> 6, t = wid & 63;
    float s = 0.f;
    for (int f = lane; f < 128; f += 64)
        s += H1[(size_t)b * 128 + f] * m1w[(size_t)f * 64 + t];
#pragma unroll
    for (int off = 32; off > 0; off >>= 1) s += __shfl_down(s, off);
    if (lane == 0) H2[(size_t)b * 64 + t] = s + m1b[t];
}

// one wave per b: out[b] = m2b[0] + dot(H2[b], m2w)   (8 waves)
__global__ __launch_bounds__(256) void mlp3_kernel(
        const float* __restrict__ H2, const float* __restrict__ m2w,
        const float* __restrict__ m2b, float* __restrict__ out) {
    int b = blockIdx.x * 4 + (threadIdx.x >> 6);
    int lane = threadIdx.x & 63;
    if (b >= BB) return;
    float s = H2[(size_t)b * 64 + lane] * m2w[lane];
#pragma unroll
    for (int off = 32; off > 0; off >>= 1) s += __shfl_down(s, off);
    if (lane == 0) out[b] = s + m2b[0];
}

// ---------------------------------------------------------------------------
extern "C" void kernel_launch(void* const* d_in, const int* in_sizes, int n_in,
                              void* d_out, int out_size, void* d_ws, size_t ws_size,
                              hipStream_t stream) {
    const float* x0 = (const float*)d_in[0];
    const float* w[5], * bi[5];
    for (int i = 0; i < 5; ++i) { w[i] = (const float*)d_in[1 + 2 * i]; bi[i] = (const float*)d_in[2 + 2 * i]; }
    const float* m0w = (const float*)d_in[11]; const float* m0b = (const float*)d_in[12];
    const float* m1w = (const float*)d_in[13]; const float* m1b = (const float*)d_in[14];
    const float* m2w = (const float*)d_in[15]; const float* m2b = (const float*)d_in[16];

    const int fouts[5] = {64, 128, 256, 512, 1024};
    const int shifts[5] = {6, 7, 8, 9, 10};
    const int woff[5] = {0, 8192, 40960, 172032, 696320};
    const size_t WTALL = 2793472;   // shorts

    float* X0 = (float*)d_ws;
    float* X1 = X0 + (size_t)BN * 1024;
    float* T  = X1 + (size_t)BN * 1024;
    float* SQ = T  + (size_t)BN * 1024;
    int*   IDX = (int*)(SQ + BN);
    unsigned short* XSh = (unsigned short*)(IDX + (size_t)BN * KK);
    unsigned short* XSl = XSh + (size_t)BN * 512;
    unsigned short* WTall = XSl + (size_t)BN * 512;
    float* GP = (float*)(WTall + WTALL);
    float* G  = GP + (size_t)GCH * BB * 1024;
    float* H1 = G + (size_t)BB * 1024;
    float* H2 = H1 + (size_t)BB * 128;
    float* bufs[2] = {X0, X1};

    xsplit3_kernel<<<(BN + 255) / 256, 256, 0, stream>>>(x0, XSh, XSl, SQ);
    wsplit_all_kernel<<<(1396736 + 255) / 256, 256, 0, stream>>>(w[0], w[1], w[2], w[3], w[4], WTall);

    int fin = 3;
    for (int l = 0; l < 5; ++l) {
        int fout = fouts[l];
        float* nxt = bufs[l & 1];
        int Fg = (l == 0) ? 32 : fin;      // padded K for MFMA path

        // d2 halves: D2a = T, D2b = nxt (both dead until gemm2 writes them)
        dim3 gg2(136, BB);   // upper-triangle 128x128 tile pairs
        knn_gram_kernel<<<gg2, 256, 0, stream>>>(XSh, XSl, SQ, T, nxt, Fg);
        knn_select_kernel<<<BN / 4, 256, 0, stream>>>(T, nxt, IDX);

        if (l == 3) {
            // 256^2-tile pipelined GEMM (K' = 3*fin via K-concat); grid 256
            // blocks = 1/CU. l2 would only fill half the CUs at this tile;
            // l4 measured faster on the 128^2 kernel (113 vs 120 us).
            int nby = (2 * fout) / 256;
            gemm2_8ph_kernel<<<dim3(64 * nby), 512, 0, stream>>>(
                XSh, XSl, WTall + woff[l], bi[l], nxt, T, fin, fout, nby);
        } else {
            dim3 gg(BN / 128, (2 * fout) / 128);
            gemm2_mfma_kernel<<<gg, 256, 0, stream>>>(XSh, XSl, WTall + woff[l], bi[l], nxt, T, Fg, fout);
        }

        if (l < 4) {
            dim3 gmg(NN / 4, BB);
            gathermax_fused_kernel<<<gmg, 256, 0, stream>>>(nxt, T, IDX, XSh, XSl, SQ, shifts[l]);
        } else {
            dim3 gmg(GCH, BB);
            gathermax_gmax_kernel<<<gmg, 256, 0, stream>>>(nxt, T, IDX, GP);
        }

        fin = fout;
    }

    gmax2_kernel<<<32, 256, 0, stream>>>(GP, G);
    mlp1_kernel<<<256, 256, 0, stream>>>(G, m0w, m0b, H1);
    mlp2_kernel<<<128, 256, 0, stream>>>(H1, m1w, m1b, H2);
    mlp3_kernel<<<2, 256, 0, stream>>>(H2, m2w, m2b, (float*)d_out);
}

// Round 8
// 983.248 us; speedup vs baseline: 1.3477x; 1.0450x over previous
//
#include <hip/hip_runtime.h>
#include <hip/hip_bf16.h>
#include <math.h>

#define BB 8
#define NN 2048
#define KK 10
#define BN (BB * NN)
#define HC 1024            // cols per d2 half (2 halves = full 2048)
#define GCH 64             // point-chunks for fused l4 gathermax+gmax

typedef __attribute__((ext_vector_type(8))) short bf16x8;
typedef __attribute__((ext_vector_type(4))) float f32x4;

__device__ inline unsigned short f2bf(float f) {
    unsigned int u = __float_as_uint(f);
    unsigned int r = u + 0x7fffu + ((u >> 16) & 1u);
    return (unsigned short)(r >> 16);
}
__device__ inline float bf2f(unsigned short h) {
    return __uint_as_float((unsigned int)h << 16);
}

// async global->LDS DMA, 16 B/lane, dest = wave-uniform base + lane*16 [m97]
__device__ __forceinline__ void async16(const void* g, void* l) {
    __builtin_amdgcn_global_load_lds(
        (const __attribute__((address_space(1))) void*)g,
        (__attribute__((address_space(3))) void*)l, 16, 0, 0);
}

// ---------------------------------------------------------------------------
// Layer 0: split x (F=3) into hi/lo bf16 padded to 32, plus row sq-norms.
__global__ void xsplit3_kernel(const float* __restrict__ x,
                               unsigned short* __restrict__ hi,
                               unsigned short* __restrict__ lo,
                               float* __restrict__ sq) {
    int row = blockIdx.x * blockDim.x + threadIdx.x;
    if (row >= BN) return;
    unsigned short hbuf[32], lbuf[32];
#pragma unroll
    for (int f = 0; f < 32; ++f) { hbuf[f] = 0; lbuf[f] = 0; }
    float s = 0.f;
#pragma unroll
    for (int f = 0; f < 3; ++f) {
        float v = x[(size_t)row * 3 + f];
        s += v * v;
        unsigned short h = f2bf(v);
        hbuf[f] = h;
        lbuf[f] = f2bf(v - bf2f(h));
    }
    sq[row] = s;
#pragma unroll
    for (int f = 0; f < 32; f += 8) {
        *(uint4*)&hi[(size_t)row * 32 + f] = *(uint4*)&hbuf[f];
        *(uint4*)&lo[(size_t)row * 32 + f] = *(uint4*)&lbuf[f];
    }
}

// ---------------------------------------------------------------------------
// All 5 layers' WT built in ONE launch (weights are layer-static).
__global__ void wsplit_all_kernel(const float* __restrict__ w0, const float* __restrict__ w1,
                                  const float* __restrict__ w2, const float* __restrict__ w3,
                                  const float* __restrict__ w4, unsigned short* __restrict__ WTall) {
    const int fins[5]  = {3, 64, 128, 256, 512};
    const int fpads[5] = {32, 64, 128, 256, 512};
    const int fouts[5] = {64, 128, 256, 512, 1024};
    const int eoff[6]  = {0, 4096, 20480, 86016, 348160, 1396736};
    const int woff[5]  = {0, 8192, 40960, 172032, 696320};
    int i = blockIdx.x * blockDim.x + threadIdx.x;
    if (i >= 1396736) return;
    int l;
    if (i < eoff[1]) l = 0; else if (i < eoff[2]) l = 1;
    else if (i < eoff[3]) l = 2; else if (i < eoff[4]) l = 3; else l = 4;
    int e = i - eoff[l];
    const float* w = (l == 0) ? w0 : (l == 1) ? w1 : (l == 2) ? w2 : (l == 3) ? w3 : w4;
    int fin = fins[l], fpad = fpads[l], fout = fouts[l];
    unsigned short* WT = WTall + woff[l];
    int op = e % (2 * fout);
    int f = e / (2 * fout);
    float v = 0.f;
    if (f < fin) {
        if (op < fout) v = w[(size_t)f * fout + op] - w[(size_t)(fin + f) * fout + op];
        else v = w[(size_t)(fin + f) * fout + (op - fout)];
    }
    unsigned short h = f2bf(v);
    unsigned short lo = f2bf(v - bf2f(h));
    WT[(size_t)op * (2 * fpad) + f] = h;
    WT[(size_t)op * (2 * fpad) + fpad + f] = lo;
}

// ---------------------------------------------------------------------------
// LAYER-0 FUSED kNN (round 8): x is only 3-D and 24 KB/batch — stage the
// whole batch in LDS and compute d2 = |xi-xj|^2 inline in the PROVEN select
// structure (wave-per-row, 32 cand/lane insertion + shfl merge, verbatim
// semantics). Eliminates gram-l0's 134 MB d2 write + select-l0's read.
// Numerics: exact-f32 d2 deviates from JAX by ~1e-7 rel; the hi/lo MFMA path
// deviates ~1e-5 and passed absmax=0 => per-row top-10 boundary slack
// >> 1e-7, and downstream max-gather is order-invariant (set-equal enough).
__global__ __launch_bounds__(256) void knn_sel0_kernel(
        const float* __restrict__ x, int* __restrict__ idx) {
    __shared__ float xs[NN * 3];                  // 24 KB
    int b = (blockIdx.x * 4) >> 11;               // 4 rows/block, same batch
    const float* xb = x + (size_t)b * NN * 3;
    for (int i = threadIdx.x; i < (NN * 3) / 4; i += 256)
        *(float4*)&xs[i * 4] = *(const float4*)&xb[i * 4];
    __syncthreads();

    int wave = threadIdx.x >> 6;
    int lane = threadIdx.x & 63;
    int row = blockIdx.x * 4 + wave;
    int rl = row & (NN - 1);
    float xi0 = xs[rl * 3], xi1 = xs[rl * 3 + 1], xi2 = xs[rl * 3 + 2];

    float bestd[KK];
    int besti[KK];
#pragma unroll
    for (int k = 0; k < KK; ++k) { bestd[k] = INFINITY; besti[k] = 0x7fffffff; }

    for (int it = 0; it < NN / 64; ++it) {
        int j = it * 64 + lane;                   // ascending per lane
        float dx = xi0 - xs[j * 3];               // stride-3 words: 2-way
        float dy = xi1 - xs[j * 3 + 1];           // bank alias = free [m136]
        float dz = xi2 - xs[j * 3 + 2];
        float d = fmaf(dx, dx, fmaf(dy, dy, dz * dz));
        if (d < bestd[KK - 1]) {
            bestd[KK - 1] = d;
            besti[KK - 1] = j;
#pragma unroll
            for (int s = KK - 1; s > 0; --s) {
                if (bestd[s] < bestd[s - 1]) {
                    float td = bestd[s]; bestd[s] = bestd[s - 1]; bestd[s - 1] = td;
                    int ti = besti[s]; besti[s] = besti[s - 1]; besti[s - 1] = ti;
                }
            }
        }
    }

    // extraction: verbatim (d, index) lexicographic shfl merge
    int h = 0;
    int mywin = 0;
    for (int s = 0; s < KK; ++s) {
        float dd = (h < KK) ? bestd[h] : INFINITY;
        int ii = (h < KK) ? besti[h] : 0x7fffffff;
        float d0 = dd; int i0 = ii;
#pragma unroll
        for (int off = 32; off > 0; off >>= 1) {
            float od = __shfl_xor(dd, off);
            int oi = __shfl_xor(ii, off);
            if (od < dd || (od == dd && oi < ii)) { dd = od; ii = oi; }
        }
        if (lane == s) mywin = ii;
        if (h < KK && i0 == ii && d0 == dd) h++;
    }
    if (lane < KK) idx[(size_t)row * KK + lane] = mywin;
}

// ---------------------------------------------------------------------------
// kNN Gram GEMM (validated round 18/20, verbatim): SYMMETRIC upper-triangle
// tiles, mirror via 64x129 LDS transpose; bf16 hi/lo 3-phase MFMA; async16;
// XOR swizzle. Layers 1-4 only (l0 replaced by knn_sel0).
__global__ __launch_bounds__(256) void knn_gram_kernel(
        const unsigned short* __restrict__ xh, const unsigned short* __restrict__ xl,
        const float* __restrict__ sq, float* __restrict__ d2a,
        float* __restrict__ d2b, int F) {
    int b = blockIdx.y;
    int t = blockIdx.x, ti = 0;
    while (t >= 16 - ti) { t -= 16 - ti; ti++; }
    int tj = ti + t;
    int row0 = ti * 128;
    int col0 = tj * 128;
    const unsigned short* xhb = xh + (size_t)b * NN * F;
    const unsigned short* xlb = xl + (size_t)b * NN * F;
    const float* sqb = sq + (size_t)b * NN;

    __shared__ __align__(16) unsigned char smem_raw[33024];
    unsigned short* Ah = (unsigned short*)smem_raw;
    unsigned short* Al = Ah + 128 * 32;
    unsigned short* Bh = Al + 128 * 32;
    unsigned short* Bl = Bh + 128 * 32;
    float* LT = (float*)smem_raw;

    int tid = threadIdx.x;
    int lane = tid & 63;
    int wave = tid >> 6;
    int wr = (wave >> 1) * 64, wc = (wave & 1) * 64;
    int l15 = lane & 15, kq = lane >> 4;
    int rsub = lane >> 2;
    int csub = (((lane & 3) ^ ((lane >> 3) & 3))) * 8;
    int kqs = (kq ^ ((l15 >> 1) & 3)) * 8;

    f32x4 acc[4][4];
#pragma unroll
    for (int mt = 0; mt < 4; ++mt)
#pragma unroll
        for (int nt = 0; nt < 4; ++nt) acc[mt][nt] = (f32x4){0.f, 0.f, 0.f, 0.f};

    for (int kc = 0; kc < F; kc += 32) {
        __syncthreads();
#pragma unroll
        for (int j = 0; j < 2; ++j) {
            int row = wave * 32 + j * 16 + rsub;
            int dsto = wave * 1024 + j * 512;
            async16(xhb + (size_t)(row0 + row) * F + kc + csub, Ah + dsto);
            async16(xlb + (size_t)(row0 + row) * F + kc + csub, Al + dsto);
            async16(xhb + (size_t)(col0 + row) * F + kc + csub, Bh + dsto);
            async16(xlb + (size_t)(col0 + row) * F + kc + csub, Bl + dsto);
        }
        __syncthreads();
        bf16x8 bh[4], bl[4];
#pragma unroll
        for (int t4 = 0; t4 < 4; ++t4) {
            bh[t4] = *(const bf16x8*)&Bh[(wc + t4 * 16 + l15) * 32 + kqs];
            bl[t4] = *(const bf16x8*)&Bl[(wc + t4 * 16 + l15) * 32 + kqs];
        }
#pragma unroll
        for (int mt = 0; mt < 4; ++mt) {
            bf16x8 ah = *(const bf16x8*)&Ah[(wr + mt * 16 + l15) * 32 + kqs];
            bf16x8 al = *(const bf16x8*)&Al[(wr + mt * 16 + l15) * 32 + kqs];
#pragma unroll
            for (int nt = 0; nt < 4; ++nt) {
                acc[mt][nt] = __builtin_amdgcn_mfma_f32_16x16x32_bf16(ah, bh[nt], acc[mt][nt], 0, 0, 0);
                acc[mt][nt] = __builtin_amdgcn_mfma_f32_16x16x32_bf16(al, bh[nt], acc[mt][nt], 0, 0, 0);
                acc[mt][nt] = __builtin_amdgcn_mfma_f32_16x16x32_bf16(ah, bl[nt], acc[mt][nt], 0, 0, 0);
            }
        }
    }
    {
        float* dst = (col0 < HC) ? d2a : d2b;
        int lc0 = col0 & (HC - 1);
#pragma unroll
        for (int mt = 0; mt < 4; ++mt) {
            int rbase = row0 + wr + mt * 16 + kq * 4;
#pragma unroll
            for (int nt = 0; nt < 4; ++nt) {
                int cc = wc + nt * 16 + l15;
                float sqc = sqb[col0 + cc];
#pragma unroll
                for (int r = 0; r < 4; ++r) {
                    float v = (sqb[rbase + r] + sqc) - 2.f * acc[mt][nt][r];
                    acc[mt][nt][r] = v;
                    dst[((size_t)b * NN + rbase + r) * HC + lc0 + cc] = v;
                }
            }
        }
    }
    if (ti != tj) {
        float* mdst = (row0 < HC) ? d2a : d2b;
        int mc0 = row0 & (HC - 1);
#pragma unroll
        for (int h = 0; h < 2; ++h) {
            __syncthreads();
            if ((wave & 1) == h) {
#pragma unroll
                for (int mt = 0; mt < 4; ++mt)
#pragma unroll
                    for (int nt = 0; nt < 4; ++nt)
#pragma unroll
                        for (int r = 0; r < 4; ++r)
                            LT[(nt * 16 + l15) * 129 + (wr + mt * 16 + kq * 4 + r)] =
                                acc[mt][nt][r];
            }
            __syncthreads();
#pragma unroll
            for (int it = 0; it < 8; ++it) {
                int v = tid + it * 256;
                int lr = v >> 5, c4 = v & 31;
                float4 val;
                val.x = LT[lr * 129 + c4 * 4];
                val.y = LT[lr * 129 + c4 * 4 + 1];
                val.z = LT[lr * 129 + c4 * 4 + 2];
                val.w = LT[lr * 129 + c4 * 4 + 3];
                *(float4*)&mdst[((size_t)b * NN + col0 + h * 64 + lr) * HC + mc0 + c4 * 4] = val;
            }
        }
    }
}

// ---------------------------------------------------------------------------
// kNN selection (validated round 15): WAVE-PER-ROW, no LDS, no barriers.
__global__ __launch_bounds__(256) void knn_select_kernel(
        const float* __restrict__ d2a, const float* __restrict__ d2b,
        int* __restrict__ idx) {
    int row = blockIdx.x * 4 + (threadIdx.x >> 6);
    int lane = threadIdx.x & 63;
    const float* ra = d2a + (size_t)row * HC;
    const float* rb = d2b + (size_t)row * HC;

    float4 v[8];
#pragma unroll
    for (int it = 0; it < 4; ++it) {
        v[it]     = *(const float4*)&ra[it * 256 + lane * 4];
        v[it + 4] = *(const float4*)&rb[it * 256 + lane * 4];
    }

    float bestd[KK];
    int besti[KK];
#pragma unroll
    for (int k = 0; k < KK; ++k) { bestd[k] = INFINITY; besti[k] = 0x7fffffff; }

#pragma unroll
    for (int it = 0; it < 8; ++it) {
        int cbase = ((it < 4) ? (it * 256) : (HC + (it - 4) * 256)) + lane * 4;
        float dv[4] = {v[it].x, v[it].y, v[it].z, v[it].w};
#pragma unroll
        for (int s4 = 0; s4 < 4; ++s4) {
            float d = dv[s4];
            if (d < bestd[KK - 1]) {
                bestd[KK - 1] = d;
                besti[KK - 1] = cbase + s4;
#pragma unroll
                for (int s = KK - 1; s > 0; --s) {
                    if (bestd[s] < bestd[s - 1]) {
                        float td = bestd[s]; bestd[s] = bestd[s - 1]; bestd[s - 1] = td;
                        int ti = besti[s]; besti[s] = besti[s - 1]; besti[s - 1] = ti;
                    }
                }
            }
        }
    }

    int h = 0;
    int mywin = 0;
    for (int s = 0; s < KK; ++s) {
        float dd = (h < KK) ? bestd[h] : INFINITY;
        int ii = (h < KK) ? besti[h] : 0x7fffffff;
        float d0 = dd; int i0 = ii;
#pragma unroll
        for (int off = 32; off > 0; off >>= 1) {
            float od = __shfl_xor(dd, off);
            int oi = __shfl_xor(ii, off);
            if (od < dd || (od == dd && oi < ii)) { dd = od; ii = oi; }
        }
        if (lane == s) mywin = ii;
        if (h < KK && i0 == ii && d0 == dd) h++;
    }
    if (lane < KK) idx[(size_t)row * KK + lane] = mywin;
}

// ---------------------------------------------------------------------------
// MFMA GEMM (validated rounds 16/17/20, verbatim): single-pass 4-tile staging
// + XOR swizzle. LDS 32 KB. Used for layers 0,1,2,4 (full-GPU 128^2 grids).
__global__ __launch_bounds__(256) void gemm2_mfma_kernel(
        const unsigned short* __restrict__ XSh, const unsigned short* __restrict__ XSl,
        const unsigned short* __restrict__ WT, const float* __restrict__ bias,
        float* __restrict__ Aout, float* __restrict__ Tout, int fin, int fout) {
    int m0 = blockIdx.x * 128;
    int n0 = blockIdx.y * 128;
    __shared__ __align__(16) unsigned short AsB[4 * 128 * 32];   // 32 KB
    unsigned short* Ah = AsB;
    unsigned short* Al = Ah + 128 * 32;
    unsigned short* Bh = Al + 128 * 32;
    unsigned short* Bl = Bh + 128 * 32;

    int tid = threadIdx.x;
    int lane = tid & 63;
    int wave = tid >> 6;
    int wr = (wave >> 1) * 64, wc = (wave & 1) * 64;
    int l15 = lane & 15, kq = lane >> 4;
    int rsub = lane >> 2;
    int csub = (((lane & 3) ^ ((lane >> 3) & 3))) * 8;
    int kqs = (kq ^ ((l15 >> 1) & 3)) * 8;
    int w2f = 2 * fin;

    f32x4 acc[4][4];
#pragma unroll
    for (int mt = 0; mt < 4; ++mt)
#pragma unroll
        for (int nt = 0; nt < 4; ++nt) acc[mt][nt] = (f32x4){0.f, 0.f, 0.f, 0.f};

    for (int kc = 0; kc < fin; kc += 32) {
        __syncthreads();
#pragma unroll
        for (int j = 0; j < 2; ++j) {
            int row = wave * 32 + j * 16 + rsub;
            int dsto = wave * 1024 + j * 512;
            async16(XSh + (size_t)(m0 + row) * fin + kc + csub, Ah + dsto);
            async16(XSl + (size_t)(m0 + row) * fin + kc + csub, Al + dsto);
            async16(WT + (size_t)(n0 + row) * w2f + kc + csub, Bh + dsto);
            async16(WT + (size_t)(n0 + row) * w2f + fin + kc + csub, Bl + dsto);
        }
        __syncthreads();
        bf16x8 bh[4], bl[4];
#pragma unroll
        for (int t = 0; t < 4; ++t) {
            bh[t] = *(const bf16x8*)&Bh[(wc + t * 16 + l15) * 32 + kqs];
            bl[t] = *(const bf16x8*)&Bl[(wc + t * 16 + l15) * 32 + kqs];
        }
#pragma unroll
        for (int mt = 0; mt < 4; ++mt) {
            bf16x8 ah = *(const bf16x8*)&Ah[(wr + mt * 16 + l15) * 32 + kqs];
            bf16x8 al = *(const bf16x8*)&Al[(wr + mt * 16 + l15) * 32 + kqs];
#pragma unroll
            for (int nt = 0; nt < 4; ++nt) {
                acc[mt][nt] = __builtin_amdgcn_mfma_f32_16x16x32_bf16(ah, bh[nt], acc[mt][nt], 0, 0, 0);
                acc[mt][nt] = __builtin_amdgcn_mfma_f32_16x16x32_bf16(al, bh[nt], acc[mt][nt], 0, 0, 0);
                acc[mt][nt] = __builtin_amdgcn_mfma_f32_16x16x32_bf16(ah, bl[nt], acc[mt][nt], 0, 0, 0);
            }
        }
    }
#pragma unroll
    for (int mt = 0; mt < 4; ++mt) {
        int mbase = m0 + wr + mt * 16 + kq * 4;
#pragma unroll
        for (int nt = 0; nt < 4; ++nt) {
            int oc = n0 + wc + nt * 16 + l15;
            f32x4 c = acc[mt][nt];
            if (oc < fout) {
                float bv = bias[oc];
#pragma unroll
                for (int r = 0; r < 4; ++r)
                    Aout[(size_t)(mbase + r) * fout + oc] = c[r] + bv;
            } else {
                int o2 = oc - fout;
#pragma unroll
                for (int r = 0; r < 4; ++r)
                    Tout[(size_t)(mbase + r) * fout + o2] = c[r];
            }
        }
    }
}

// ---------------------------------------------------------------------------
// 256^2-tile 8-phase pipelined GEMM (round-1 verbatim, refcheck'd) — layer 3
// only (grid 256 = 1 block/CU; measured best at l3 in R5).
__device__ __forceinline__ const unsigned short* tbaseA(
        const unsigned short* XSh, const unsigned short* XSl, int F, int t) {
    int ko = t * 64;
    if (ko < F) return XSh + ko;
    if (ko < 2 * F) return XSl + (ko - F);
    return XSh + (ko - 2 * F);
}
__device__ __forceinline__ const unsigned short* tbaseB(
        const unsigned short* WT, int F, int t) {
    int ko = t * 64;
    if (ko < F) return WT + ko;
    if (ko < 2 * F) return WT + (ko - F);       // hi again
    return WT + F + (ko - 2 * F);               // lo half of the row
}

#define GBAR() asm volatile("s_barrier" ::: "memory")

__global__ __launch_bounds__(512, 2) void gemm2_8ph_kernel(
        const unsigned short* __restrict__ XSh, const unsigned short* __restrict__ XSl,
        const unsigned short* __restrict__ WT, const float* __restrict__ bias,
        float* __restrict__ Aout, float* __restrict__ Tout, int F, int fout, int nby) {
    __shared__ __align__(16) unsigned short Lds[65536];   // 128 KiB

    int nwg = gridDim.x;
    int bid = blockIdx.x;
    int q = nwg >> 3;
    int swz = (bid & 7) * q + (bid >> 3);
    int by = swz % nby;
    int bx = swz / nby;
    int m0 = bx * 256, n0 = by * 256;

    int tid = threadIdx.x;
    int lane = tid & 63;
    int wave = tid >> 6;
    int mw = wave >> 2;
    int nw = wave & 3;
    int l15 = lane & 15, kq = lane >> 4;
    int rx7 = l15 & 7;

    int isA = (wave < 4);
    size_t rowmul = isA ? (size_t)F : (size_t)(2 * F);
    int orgn = isA ? m0 : n0;
    int r8 = lane >> 3;
    int cb8 = ((lane & 7) ^ r8) * 8;
    int subb = (wave & 3) * 8;
    int ldsoA = isA ? 0 : 16384;

    int nt = (3 * F) >> 6;

    f32x4 acc[8][4];
#pragma unroll
    for (int mt = 0; mt < 8; ++mt)
#pragma unroll
        for (int nn = 0; nn < 4; ++nn) acc[mt][nn] = (f32x4){0.f, 0.f, 0.f, 0.f};

    auto stage = [&](const unsigned short* tb, int par, int j) {
        int sub = subb + j;
        async16(tb + (size_t)(orgn + sub * 8 + r8) * rowmul + cb8,
                Lds + par * 32768 + ldsoA + sub * 512);
    };

    {
        const unsigned short* t0 = isA ? tbaseA(XSh, XSl, F, 0) : tbaseB(WT, F, 0);
        const unsigned short* t1 = isA ? tbaseA(XSh, XSl, F, 1) : tbaseB(WT, F, 1);
#pragma unroll
        for (int j = 0; j < 8; ++j) stage(t0, 0, j);
#pragma unroll
        for (int j = 0; j < 4; ++j) stage(t1, 1, j);
    }
    asm volatile("s_waitcnt vmcnt(4)" ::: "memory");
    GBAR();

    for (int t = 0; t < nt; ++t) {
        const unsigned short* Ab = Lds + (t & 1) * 32768;
        const unsigned short* Bb = Ab + 16384;
        bool s1 = (t + 1 < nt), s2 = (t + 2 < nt);
        const unsigned short* tb1 = s1 ? (isA ? tbaseA(XSh, XSl, F, t + 1)
                                              : tbaseB(WT, F, t + 1)) : XSh;
        const unsigned short* tb2 = s2 ? (isA ? tbaseA(XSh, XSl, F, t + 2)
                                              : tbaseB(WT, F, t + 2)) : XSh;
        int p1 = (t + 1) & 1, p0 = t & 1;

        bf16x8 aF[4][2], bA[2][2], bB[2][2];

#pragma unroll
        for (int mt = 0; mt < 4; ++mt)
#pragma unroll
            for (int kf = 0; kf < 2; ++kf)
                aF[mt][kf] = *(const bf16x8*)&Ab[(mw * 128 + mt * 16 + l15) * 64 +
                                                 ((kf * 4 + kq) ^ rx7) * 8];
#pragma unroll
        for (int nn = 0; nn < 2; ++nn)
#pragma unroll
            for (int kf = 0; kf < 2; ++kf)
                bA[nn][kf] = *(const bf16x8*)&Bb[(nw * 64 + nn * 16 + l15) * 64 +
                                                 ((kf * 4 + kq) ^ rx7) * 8];
        if (s1) { stage(tb1, p1, 4); stage(tb1, p1, 5); }
        GBAR();
        __builtin_amdgcn_s_setprio(1);
#pragma unroll
        for (int mt = 0; mt < 4; ++mt)
#pragma unroll
            for (int nn = 0; nn < 2; ++nn) {
                acc[mt][nn] = __builtin_amdgcn_mfma_f32_16x16x32_bf16(aF[mt][0], bA[nn][0], acc[mt][nn], 0, 0, 0);
                acc[mt][nn] = __builtin_amdgcn_mfma_f32_16x16x32_bf16(aF[mt][1], bA[nn][1], acc[mt][nn], 0, 0, 0);
            }
        __builtin_amdgcn_s_setprio(0);
        GBAR();

#pragma unroll
        for (int nn = 0; nn < 2; ++nn)
#pragma unroll
            for (int kf = 0; kf < 2; ++kf)
                bB[nn][kf] = *(const bf16x8*)&Bb[(nw * 64 + (nn + 2) * 16 + l15) * 64 +
                                                 ((kf * 4 + kq) ^ rx7) * 8];
        if (s1) { stage(tb1, p1, 6); stage(tb1, p1, 7); }
        GBAR();
        __builtin_amdgcn_s_setprio(1);
#pragma unroll
        for (int mt = 0; mt < 4; ++mt)
#pragma unroll
            for (int nn = 0; nn < 2; ++nn) {
                acc[mt][nn + 2] = __builtin_amdgcn_mfma_f32_16x16x32_bf16(aF[mt][0], bB[nn][0], acc[mt][nn + 2], 0, 0, 0);
                acc[mt][nn + 2] = __builtin_amdgcn_mfma_f32_16x16x32_bf16(aF[mt][1], bB[nn][1], acc[mt][nn + 2], 0, 0, 0);
            }
        __builtin_amdgcn_s_setprio(0);
        GBAR();

#pragma unroll
        for (int mt = 0; mt < 4; ++mt)
#pragma unroll
            for (int kf = 0; kf < 2; ++kf)
                aF[mt][kf] = *(const bf16x8*)&Ab[(mw * 128 + (mt + 4) * 16 + l15) * 64 +
                                                 ((kf * 4 + kq) ^ rx7) * 8];
        GBAR();
        __builtin_amdgcn_s_setprio(1);
#pragma unroll
        for (int mt = 0; mt < 4; ++mt)
#pragma unroll
            for (int nn = 0; nn < 2; ++nn) {
                acc[mt + 4][nn] = __builtin_amdgcn_mfma_f32_16x16x32_bf16(aF[mt][0], bA[nn][0], acc[mt + 4][nn], 0, 0, 0);
                acc[mt + 4][nn] = __builtin_amdgcn_mfma_f32_16x16x32_bf16(aF[mt][1], bA[nn][1], acc[mt + 4][nn], 0, 0, 0);
            }
        __builtin_amdgcn_s_setprio(0);
        GBAR();

        if (s2) { stage(tb2, p0, 0); stage(tb2, p0, 1); stage(tb2, p0, 2); stage(tb2, p0, 3); }
        GBAR();
        __builtin_amdgcn_s_setprio(1);
#pragma unroll
        for (int mt = 0; mt < 4; ++mt)
#pragma unroll
            for (int nn = 0; nn < 2; ++nn) {
                acc[mt + 4][nn + 2] = __builtin_amdgcn_mfma_f32_16x16x32_bf16(aF[mt][0], bB[nn][0], acc[mt + 4][nn + 2], 0, 0, 0);
                acc[mt + 4][nn + 2] = __builtin_amdgcn_mfma_f32_16x16x32_bf16(aF[mt][1], bB[nn][1], acc[mt + 4][nn + 2], 0, 0, 0);
            }
        __builtin_amdgcn_s_setprio(0);
        if (s2)      asm volatile("s_waitcnt vmcnt(4)" ::: "memory");
        else if (s1) asm volatile("s_waitcnt vmcnt(0)" ::: "memory");
        GBAR();
    }

#pragma unroll
    for (int mt = 0; mt < 8; ++mt) {
        int mbase = m0 + mw * 128 + mt * 16 + kq * 4;
#pragma unroll
        for (int nn = 0; nn < 4; ++nn) {
            int oc = n0 + nw * 64 + nn * 16 + l15;
            f32x4 c = acc[mt][nn];
            if (oc < fout) {
                float bv = bias[oc];
#pragma unroll
                for (int r = 0; r < 4; ++r)
                    Aout[(size_t)(mbase + r) * fout + oc] = c[r] + bv;
            } else {
                int o2 = oc - fout;
#pragma unroll
                for (int r = 0; r < 4; ++r)
                    Tout[(size_t)(mbase + r) * fout + o2] = c[r];
            }
        }
    }
}

// ---------------------------------------------------------------------------
// FUSED gathermax (layers 0-3): wave-per-row; writes bf16 splits + sq only.
__global__ __launch_bounds__(256) void gathermax_fused_kernel(
        const float* __restrict__ A, const float* __restrict__ T,
        const int* __restrict__ idx, unsigned short* __restrict__ hi,
        unsigned short* __restrict__ lo, float* __restrict__ sq, int shift) {
    int b = blockIdx.y;
    int wave = threadIdx.x >> 6;
    int lane = threadIdx.x & 63;
    int pnl = blockIdx.x * 4 + wave;
    int pn = (b << 11) + pnl;
    int fout = 1 << shift;
    int nf4 = fout >> 2;
    const float* Tb = T + ((size_t)b << 11) * fout;
    const int* ip = idx + (size_t)pn * KK;
    int j[KK];
#pragma unroll
    for (int k = 0; k < KK; ++k) j[k] = ip[k];

    float s = 0.f;
    for (int f4 = lane; f4 < nf4; f4 += 64) {
        int o = f4 * 4;
        float4 m = {-INFINITY, -INFINITY, -INFINITY, -INFINITY};
#pragma unroll
        for (int k = 0; k < KK; ++k) {
            float4 t = *(const float4*)&Tb[(size_t)j[k] * fout + o];
            m.x = fmaxf(m.x, t.x); m.y = fmaxf(m.y, t.y);
            m.z = fmaxf(m.z, t.z); m.w = fmaxf(m.w, t.w);
        }
        float4 a = *(const float4*)&A[(size_t)pn * fout + o];
        float h4[4];
        h4[0] = a.x + m.x; h4[1] = a.y + m.y; h4[2] = a.z + m.z; h4[3] = a.w + m.w;
        uint2 uh, ul;
        unsigned short hs[4], ls[4];
#pragma unroll
        for (int q = 0; q < 4; ++q) {
            float h = h4[q] > 0.f ? h4[q] : 0.2f * h4[q];
            s += h * h;
            unsigned short hh = f2bf(h);
            hs[q] = hh;
            ls[q] = f2bf(h - bf2f(hh));
        }
        uh.x = (unsigned)hs[0] | ((unsigned)hs[1] << 16);
        uh.y = (unsigned)hs[2] | ((unsigned)hs[3] << 16);
        ul.x = (unsigned)ls[0] | ((unsigned)ls[1] << 16);
        ul.y = (unsigned)ls[2] | ((unsigned)ls[3] << 16);
        *(uint2*)&hi[(size_t)pn * fout + o] = uh;
        *(uint2*)&lo[(size_t)pn * fout + o] = ul;
    }
#pragma unroll
    for (int off = 32; off > 0; off >>= 1) s += __shfl_down(s, off);
    if (lane == 0) sq[pn] = s;
}

// ---------------------------------------------------------------------------
// FUSED l4 gathermax + gmax pass 1 (validated round 20).
__global__ __launch_bounds__(256) void gathermax_gmax_kernel(
        const float* __restrict__ A, const float* __restrict__ T,
        const int* __restrict__ idx, float* __restrict__ gp) {
    int chunk = blockIdx.x;
    int b = blockIdx.y;
    int o = threadIdx.x * 4;
    const float* Tb = T + ((size_t)b << 11) * 1024;
    float4 gm = {-INFINITY, -INFINITY, -INFINITY, -INFINITY};
    for (int p = 0; p < NN / GCH; ++p) {
        int pnl = chunk * (NN / GCH) + p;
        int pn = (b << 11) + pnl;
        const int* ip = idx + (size_t)pn * KK;
        float4 m = {-INFINITY, -INFINITY, -INFINITY, -INFINITY};
#pragma unroll
        for (int k = 0; k < KK; ++k) {
            int j = ip[k];
            float4 t = *(const float4*)&Tb[(size_t)j * 1024 + o];
            m.x = fmaxf(m.x, t.x); m.y = fmaxf(m.y, t.y);
            m.z = fmaxf(m.z, t.z); m.w = fmaxf(m.w, t.w);
        }
        float4 a = *(const float4*)&A[(size_t)pn * 1024 + o];
        float4 h;
        h.x = a.x + m.x; h.y = a.y + m.y; h.z = a.z + m.z; h.w = a.w + m.w;
        h.x = h.x > 0.f ? h.x : 0.2f * h.x;
        h.y = h.y > 0.f ? h.y : 0.2f * h.y;
        h.z = h.z > 0.f ? h.z : 0.2f * h.z;
        h.w = h.w > 0.f ? h.w : 0.2f * h.w;
        gm.x = fmaxf(gm.x, h.x); gm.y = fmaxf(gm.y, h.y);
        gm.z = fmaxf(gm.z, h.z); gm.w = fmaxf(gm.w, h.w);
    }
    *(float4*)&gp[((size_t)chunk * BB + b) * 1024 + o] = gm;
}

// ---------------------------------------------------------------------------
// Parallel tail: gmax2 (coalesced) then wave-per-output MLP stages.
__global__ void gmax2_kernel(const float* __restrict__ gp, float* __restrict__ g) {
    int i = blockIdx.x * 256 + threadIdx.x;      // 0..8191
    int b = i >> 10, o = i & 1023;
    float m = -INFINITY;
    for (int c = 0; c < GCH; ++c) m = fmaxf(m, gp[((size_t)c * BB + b) * 1024 + o]);
    g[(size_t)b * 1024 + o] = m;
}

// one wave per (b,t): H1[b][t] = m0b[t] + dot(G[b], m0w[:,t])   (1024 waves)
__global__ __launch_bounds__(256) void mlp1_kernel(
        const float* __restrict__ g, const float* __restrict__ m0w,
        const float* __restrict__ m0b, float* __restrict__ H1) {
    int wid = blockIdx.x * 4 + (threadIdx.x >> 6);
    int lane = threadIdx.x & 63;
    int b = wid >> 7, t = wid & 127;
    float s = 0.f;
    for (int f = lane; f < 1024; f += 64)
        s += g[(size_t)b * 1024 + f] * m0w[(size_t)f * 128 + t];
#pragma unroll
    for (int off = 32; off > 0; off >>= 1) s += __shfl_down(s, off);
    if (lane == 0) H1[(size_t)b * 128 + t] = s + m0b[t];
}

// one wave per (b,t): H2[b][t] = m1b[t] + dot(H1[b], m1w[:,t])   (512 waves)
__global__ __launch_bounds__(256) void mlp2_kernel(
        const float* __restrict__ H1, const float* __restrict__ m1w,
        const float* __restrict__ m1b, float* __restrict__ H2) {
    int wid = blockIdx.x * 4 + (threadIdx.x >> 6);
    int lane = threadIdx.x & 63;
    int b = wid >> 6, t = wid & 63;
    float s = 0.f;
    for (int f = lane; f < 128; f += 64)
        s += H1[(size_t)b * 128 + f] * m1w[(size_t)f * 64 + t];
#pragma unroll
    for (int off = 32; off > 0; off >>= 1) s += __shfl_down(s, off);
    if (lane == 0) H2[(size_t)b * 64 + t] = s + m1b[t];
}

// one wave per b: out[b] = m2b[0] + dot(H2[b], m2w)   (8 waves)
__global__ __launch_bounds__(256) void mlp3_kernel(
        const float* __restrict__ H2, const float* __restrict__ m2w,
        const float* __restrict__ m2b, float* __restrict__ out) {
    int b = blockIdx.x * 4 + (threadIdx.x >> 6);
    int lane = threadIdx.x & 63;
    if (b >= BB) return;
    float s = H2[(size_t)b * 64 + lane] * m2w[lane];
#pragma unroll
    for (int off = 32; off > 0; off >>= 1) s += __shfl_down(s, off);
    if (lane == 0) out[b] = s + m2b[0];
}

// ---------------------------------------------------------------------------
extern "C" void kernel_launch(void* const* d_in, const int* in_sizes, int n_in,
                              void* d_out, int out_size, void* d_ws, size_t ws_size,
                              hipStream_t stream) {
    const float* x0 = (const float*)d_in[0];
    const float* w[5], * bi[5];
    for (int i = 0; i < 5; ++i) { w[i] = (const float*)d_in[1 + 2 * i]; bi[i] = (const float*)d_in[2 + 2 * i]; }
    const float* m0w = (const float*)d_in[11]; const float* m0b = (const float*)d_in[12];
    const float* m1w = (const float*)d_in[13]; const float* m1b = (const float*)d_in[14];
    const float* m2w = (const float*)d_in[15]; const float* m2b = (const float*)d_in[16];

    const int fouts[5] = {64, 128, 256, 512, 1024};
    const int shifts[5] = {6, 7, 8, 9, 10};
    const int woff[5] = {0, 8192, 40960, 172032, 696320};
    const size_t WTALL = 2793472;   // shorts

    float* X0 = (float*)d_ws;
    float* X1 = X0 + (size_t)BN * 1024;
    float* T  = X1 + (size_t)BN * 1024;
    float* SQ = T  + (size_t)BN * 1024;
    int*   IDX = (int*)(SQ + BN);
    unsigned short* XSh = (unsigned short*)(IDX + (size_t)BN * KK);
    unsigned short* XSl = XSh + (size_t)BN * 512;
    unsigned short* WTall = XSl + (size_t)BN * 512;
    float* GP = (float*)(WTall + WTALL);
    float* G  = GP + (size_t)GCH * BB * 1024;
    float* H1 = G + (size_t)BB * 1024;
    float* H2 = H1 + (size_t)BB * 128;
    float* bufs[2] = {X0, X1};

    xsplit3_kernel<<<(BN + 255) / 256, 256, 0, stream>>>(x0, XSh, XSl, SQ);
    wsplit_all_kernel<<<(1396736 + 255) / 256, 256, 0, stream>>>(w[0], w[1], w[2], w[3], w[4], WTall);

    // layer-0 kNN: direct 3-D distance select (no d2 materialization)
    knn_sel0_kernel<<<BN / 4, 256, 0, stream>>>(x0, IDX);

    int fin = 3;
    for (int l = 0; l < 5; ++l) {
        int fout = fouts[l];
        float* nxt = bufs[l & 1];
        int Fg = (l == 0) ? 32 : fin;      // padded K for MFMA path

        if (l > 0) {
            // d2 halves: D2a = T, D2b = nxt (both dead until gemm2 writes)
            dim3 gg2(136, BB);   // upper-triangle 128x128 tile pairs
            knn_gram_kernel<<<gg2, 256, 0, stream>>>(XSh, XSl, SQ, T, nxt, Fg);
            knn_select_kernel<<<BN / 4, 256, 0, stream>>>(T, nxt, IDX);
        }

        if (l == 3) {
            // 256^2-tile pipelined GEMM (K' = 3*fin via K-concat); grid 256
            // blocks = 1/CU. l2 would only fill half the CUs at this tile;
            // l4 measured faster on the 128^2 kernel (113 vs 120 us).
            int nby = (2 * fout) / 256;
            gemm2_8ph_kernel<<<dim3(64 * nby), 512, 0, stream>>>(
                XSh, XSl, WTall + woff[l], bi[l], nxt, T, fin, fout, nby);
        } else {
            dim3 gg(BN / 128, (2 * fout) / 128);
            gemm2_mfma_kernel<<<gg, 256, 0, stream>>>(XSh, XSl, WTall + woff[l], bi[l], nxt, T, Fg, fout);
        }

        if (l < 4) {
            dim3 gmg(NN / 4, BB);
            gathermax_fused_kernel<<<gmg, 256, 0, stream>>>(nxt, T, IDX, XSh, XSl, SQ, shifts[l]);
        } else {
            dim3 gmg(GCH, BB);
            gathermax_gmax_kernel<<<gmg, 256, 0, stream>>>(nxt, T, IDX, GP);
        }

        fin = fout;
    }

    gmax2_kernel<<<32, 256, 0, stream>>>(GP, G);
    mlp1_kernel<<<256, 256, 0, stream>>>(G, m0w, m0b, H1);
    mlp2_kernel<<<128, 256, 0, stream>>>(H1, m1w, m1b, H2);
    mlp3_kernel<<<2, 256, 0, stream>>>(H2, m2w, m2b, (float*)d_out);
}

// Round 9
// 950.077 us; speedup vs baseline: 1.3947x; 1.0349x over previous
//
#include <hip/hip_runtime.h>
#include <hip/hip_bf16.h>
#include <math.h>

#define BB 8
#define NN 2048
#define KK 10
#define BN (BB * NN)
#define HC 1024            // cols per d2 half (2 halves = full 2048)
#define GCH 64             // point-chunks for fused l4 gathermax+gmax

typedef __attribute__((ext_vector_type(8))) short bf16x8;
typedef __attribute__((ext_vector_type(4))) float f32x4;

__device__ inline unsigned short f2bf(float f) {
    unsigned int u = __float_as_uint(f);
    unsigned int r = u + 0x7fffu + ((u >> 16) & 1u);
    return (unsigned short)(r >> 16);
}
__device__ inline float bf2f(unsigned short h) {
    return __uint_as_float((unsigned int)h << 16);
}

// async global->LDS DMA, 16 B/lane, dest = wave-uniform base + lane*16 [m97]
__device__ __forceinline__ void async16(const void* g, void* l) {
    __builtin_amdgcn_global_load_lds(
        (const __attribute__((address_space(1))) void*)g,
        (__attribute__((address_space(3))) void*)l, 16, 0, 0);
}

// ---------------------------------------------------------------------------
// Layer 0: split x (F=3) into hi/lo bf16 padded to 32, plus row sq-norms.
__global__ void xsplit3_kernel(const float* __restrict__ x,
                               unsigned short* __restrict__ hi,
                               unsigned short* __restrict__ lo,
                               float* __restrict__ sq) {
    int row = blockIdx.x * blockDim.x + threadIdx.x;
    if (row >= BN) return;
    unsigned short hbuf[32], lbuf[32];
#pragma unroll
    for (int f = 0; f < 32; ++f) { hbuf[f] = 0; lbuf[f] = 0; }
    float s = 0.f;
#pragma unroll
    for (int f = 0; f < 3; ++f) {
        float v = x[(size_t)row * 3 + f];
        s += v * v;
        unsigned short h = f2bf(v);
        hbuf[f] = h;
        lbuf[f] = f2bf(v - bf2f(h));
    }
    sq[row] = s;
#pragma unroll
    for (int f = 0; f < 32; f += 8) {
        *(uint4*)&hi[(size_t)row * 32 + f] = *(uint4*)&hbuf[f];
        *(uint4*)&lo[(size_t)row * 32 + f] = *(uint4*)&lbuf[f];
    }
}

// ---------------------------------------------------------------------------
// All 5 layers' WT built in ONE launch (weights are layer-static).
__global__ void wsplit_all_kernel(const float* __restrict__ w0, const float* __restrict__ w1,
                                  const float* __restrict__ w2, const float* __restrict__ w3,
                                  const float* __restrict__ w4, unsigned short* __restrict__ WTall) {
    const int fins[5]  = {3, 64, 128, 256, 512};
    const int fpads[5] = {32, 64, 128, 256, 512};
    const int fouts[5] = {64, 128, 256, 512, 1024};
    const int eoff[6]  = {0, 4096, 20480, 86016, 348160, 1396736};
    const int woff[5]  = {0, 8192, 40960, 172032, 696320};
    int i = blockIdx.x * blockDim.x + threadIdx.x;
    if (i >= 1396736) return;
    int l;
    if (i < eoff[1]) l = 0; else if (i < eoff[2]) l = 1;
    else if (i < eoff[3]) l = 2; else if (i < eoff[4]) l = 3; else l = 4;
    int e = i - eoff[l];
    const float* w = (l == 0) ? w0 : (l == 1) ? w1 : (l == 2) ? w2 : (l == 3) ? w3 : w4;
    int fin = fins[l], fpad = fpads[l], fout = fouts[l];
    unsigned short* WT = WTall + woff[l];
    int op = e % (2 * fout);
    int f = e / (2 * fout);
    float v = 0.f;
    if (f < fin) {
        if (op < fout) v = w[(size_t)f * fout + op] - w[(size_t)(fin + f) * fout + op];
        else v = w[(size_t)(fin + f) * fout + (op - fout)];
    }
    unsigned short h = f2bf(v);
    unsigned short lo = f2bf(v - bf2f(h));
    WT[(size_t)op * (2 * fpad) + f] = h;
    WT[(size_t)op * (2 * fpad) + fpad + f] = lo;
}

// ---------------------------------------------------------------------------
// LAYER-0 FUSED kNN (validated round 8): x is 3-D and 24 KB/batch — stage the
// whole batch in LDS and compute d2 = |xi-xj|^2 inline in the PROVEN select
// structure (wave-per-row, 32 cand/lane insertion + shfl merge, verbatim
// semantics). Eliminates gram-l0's 134 MB d2 write + select-l0's read
// (-44 us same-harness, absmax 0.0).
__global__ __launch_bounds__(256) void knn_sel0_kernel(
        const float* __restrict__ x, int* __restrict__ idx) {
    __shared__ float xs[NN * 3];                  // 24 KB
    int b = (blockIdx.x * 4) >> 11;               // 4 rows/block, same batch
    const float* xb = x + (size_t)b * NN * 3;
    for (int i = threadIdx.x; i < (NN * 3) / 4; i += 256)
        *(float4*)&xs[i * 4] = *(const float4*)&xb[i * 4];
    __syncthreads();

    int wave = threadIdx.x >> 6;
    int lane = threadIdx.x & 63;
    int row = blockIdx.x * 4 + wave;
    int rl = row & (NN - 1);
    float xi0 = xs[rl * 3], xi1 = xs[rl * 3 + 1], xi2 = xs[rl * 3 + 2];

    float bestd[KK];
    int besti[KK];
#pragma unroll
    for (int k = 0; k < KK; ++k) { bestd[k] = INFINITY; besti[k] = 0x7fffffff; }

    for (int it = 0; it < NN / 64; ++it) {
        int j = it * 64 + lane;                   // ascending per lane
        float dx = xi0 - xs[j * 3];               // stride-3 words: 2-way
        float dy = xi1 - xs[j * 3 + 1];           // bank alias = free [m136]
        float dz = xi2 - xs[j * 3 + 2];
        float d = fmaf(dx, dx, fmaf(dy, dy, dz * dz));
        if (d < bestd[KK - 1]) {
            bestd[KK - 1] = d;
            besti[KK - 1] = j;
#pragma unroll
            for (int s = KK - 1; s > 0; --s) {
                if (bestd[s] < bestd[s - 1]) {
                    float td = bestd[s]; bestd[s] = bestd[s - 1]; bestd[s - 1] = td;
                    int ti = besti[s]; besti[s] = besti[s - 1]; besti[s - 1] = ti;
                }
            }
        }
    }

    // extraction: verbatim (d, index) lexicographic shfl merge
    int h = 0;
    int mywin = 0;
    for (int s = 0; s < KK; ++s) {
        float dd = (h < KK) ? bestd[h] : INFINITY;
        int ii = (h < KK) ? besti[h] : 0x7fffffff;
        float d0 = dd; int i0 = ii;
#pragma unroll
        for (int off = 32; off > 0; off >>= 1) {
            float od = __shfl_xor(dd, off);
            int oi = __shfl_xor(ii, off);
            if (od < dd || (od == dd && oi < ii)) { dd = od; ii = oi; }
        }
        if (lane == s) mywin = ii;
        if (h < KK && i0 == ii && d0 == dd) h++;
    }
    if (lane < KK) idx[(size_t)row * KK + lane] = mywin;
}

// ---------------------------------------------------------------------------
// kNN Gram GEMM (validated round 18/20, verbatim): SYMMETRIC upper-triangle
// tiles, mirror via 64x129 LDS transpose; bf16 hi/lo 3-phase MFMA; async16;
// XOR swizzle. Layers 1-4 only (l0 replaced by knn_sel0).
__global__ __launch_bounds__(256) void knn_gram_kernel(
        const unsigned short* __restrict__ xh, const unsigned short* __restrict__ xl,
        const float* __restrict__ sq, float* __restrict__ d2a,
        float* __restrict__ d2b, int F) {
    int b = blockIdx.y;
    int t = blockIdx.x, ti = 0;
    while (t >= 16 - ti) { t -= 16 - ti; ti++; }
    int tj = ti + t;
    int row0 = ti * 128;
    int col0 = tj * 128;
    const unsigned short* xhb = xh + (size_t)b * NN * F;
    const unsigned short* xlb = xl + (size_t)b * NN * F;
    const float* sqb = sq + (size_t)b * NN;

    __shared__ __align__(16) unsigned char smem_raw[33024];
    unsigned short* Ah = (unsigned short*)smem_raw;
    unsigned short* Al = Ah + 128 * 32;
    unsigned short* Bh = Al + 128 * 32;
    unsigned short* Bl = Bh + 128 * 32;
    float* LT = (float*)smem_raw;

    int tid = threadIdx.x;
    int lane = tid & 63;
    int wave = tid >> 6;
    int wr = (wave >> 1) * 64, wc = (wave & 1) * 64;
    int l15 = lane & 15, kq = lane >> 4;
    int rsub = lane >> 2;
    int csub = (((lane & 3) ^ ((lane >> 3) & 3))) * 8;
    int kqs = (kq ^ ((l15 >> 1) & 3)) * 8;

    f32x4 acc[4][4];
#pragma unroll
    for (int mt = 0; mt < 4; ++mt)
#pragma unroll
        for (int nt = 0; nt < 4; ++nt) acc[mt][nt] = (f32x4){0.f, 0.f, 0.f, 0.f};

    for (int kc = 0; kc < F; kc += 32) {
        __syncthreads();
#pragma unroll
        for (int j = 0; j < 2; ++j) {
            int row = wave * 32 + j * 16 + rsub;
            int dsto = wave * 1024 + j * 512;
            async16(xhb + (size_t)(row0 + row) * F + kc + csub, Ah + dsto);
            async16(xlb + (size_t)(row0 + row) * F + kc + csub, Al + dsto);
            async16(xhb + (size_t)(col0 + row) * F + kc + csub, Bh + dsto);
            async16(xlb + (size_t)(col0 + row) * F + kc + csub, Bl + dsto);
        }
        __syncthreads();
        bf16x8 bh[4], bl[4];
#pragma unroll
        for (int t4 = 0; t4 < 4; ++t4) {
            bh[t4] = *(const bf16x8*)&Bh[(wc + t4 * 16 + l15) * 32 + kqs];
            bl[t4] = *(const bf16x8*)&Bl[(wc + t4 * 16 + l15) * 32 + kqs];
        }
#pragma unroll
        for (int mt = 0; mt < 4; ++mt) {
            bf16x8 ah = *(const bf16x8*)&Ah[(wr + mt * 16 + l15) * 32 + kqs];
            bf16x8 al = *(const bf16x8*)&Al[(wr + mt * 16 + l15) * 32 + kqs];
#pragma unroll
            for (int nt = 0; nt < 4; ++nt) {
                acc[mt][nt] = __builtin_amdgcn_mfma_f32_16x16x32_bf16(ah, bh[nt], acc[mt][nt], 0, 0, 0);
                acc[mt][nt] = __builtin_amdgcn_mfma_f32_16x16x32_bf16(al, bh[nt], acc[mt][nt], 0, 0, 0);
                acc[mt][nt] = __builtin_amdgcn_mfma_f32_16x16x32_bf16(ah, bl[nt], acc[mt][nt], 0, 0, 0);
            }
        }
    }
    {
        float* dst = (col0 < HC) ? d2a : d2b;
        int lc0 = col0 & (HC - 1);
#pragma unroll
        for (int mt = 0; mt < 4; ++mt) {
            int rbase = row0 + wr + mt * 16 + kq * 4;
#pragma unroll
            for (int nt = 0; nt < 4; ++nt) {
                int cc = wc + nt * 16 + l15;
                float sqc = sqb[col0 + cc];
#pragma unroll
                for (int r = 0; r < 4; ++r) {
                    float v = (sqb[rbase + r] + sqc) - 2.f * acc[mt][nt][r];
                    acc[mt][nt][r] = v;
                    dst[((size_t)b * NN + rbase + r) * HC + lc0 + cc] = v;
                }
            }
        }
    }
    if (ti != tj) {
        float* mdst = (row0 < HC) ? d2a : d2b;
        int mc0 = row0 & (HC - 1);
#pragma unroll
        for (int h = 0; h < 2; ++h) {
            __syncthreads();
            if ((wave & 1) == h) {
#pragma unroll
                for (int mt = 0; mt < 4; ++mt)
#pragma unroll
                    for (int nt = 0; nt < 4; ++nt)
#pragma unroll
                        for (int r = 0; r < 4; ++r)
                            LT[(nt * 16 + l15) * 129 + (wr + mt * 16 + kq * 4 + r)] =
                                acc[mt][nt][r];
            }
            __syncthreads();
#pragma unroll
            for (int it = 0; it < 8; ++it) {
                int v = tid + it * 256;
                int lr = v >> 5, c4 = v & 31;
                float4 val;
                val.x = LT[lr * 129 + c4 * 4];
                val.y = LT[lr * 129 + c4 * 4 + 1];
                val.z = LT[lr * 129 + c4 * 4 + 2];
                val.w = LT[lr * 129 + c4 * 4 + 3];
                *(float4*)&mdst[((size_t)b * NN + col0 + h * 64 + lr) * HC + mc0 + c4 * 4] = val;
            }
        }
    }
}

// ---------------------------------------------------------------------------
// kNN selection (validated round 15): WAVE-PER-ROW, no LDS, no barriers.
__global__ __launch_bounds__(256) void knn_select_kernel(
        const float* __restrict__ d2a, const float* __restrict__ d2b,
        int* __restrict__ idx) {
    int row = blockIdx.x * 4 + (threadIdx.x >> 6);
    int lane = threadIdx.x & 63;
    const float* ra = d2a + (size_t)row * HC;
    const float* rb = d2b + (size_t)row * HC;

    float4 v[8];
#pragma unroll
    for (int it = 0; it < 4; ++it) {
        v[it]     = *(const float4*)&ra[it * 256 + lane * 4];
        v[it + 4] = *(const float4*)&rb[it * 256 + lane * 4];
    }

    float bestd[KK];
    int besti[KK];
#pragma unroll
    for (int k = 0; k < KK; ++k) { bestd[k] = INFINITY; besti[k] = 0x7fffffff; }

#pragma unroll
    for (int it = 0; it < 8; ++it) {
        int cbase = ((it < 4) ? (it * 256) : (HC + (it - 4) * 256)) + lane * 4;
        float dv[4] = {v[it].x, v[it].y, v[it].z, v[it].w};
#pragma unroll
        for (int s4 = 0; s4 < 4; ++s4) {
            float d = dv[s4];
            if (d < bestd[KK - 1]) {
                bestd[KK - 1] = d;
                besti[KK - 1] = cbase + s4;
#pragma unroll
                for (int s = KK - 1; s > 0; --s) {
                    if (bestd[s] < bestd[s - 1]) {
                        float td = bestd[s]; bestd[s] = bestd[s - 1]; bestd[s - 1] = td;
                        int ti = besti[s]; besti[s] = besti[s - 1]; besti[s - 1] = ti;
                    }
                }
            }
        }
    }

    int h = 0;
    int mywin = 0;
    for (int s = 0; s < KK; ++s) {
        float dd = (h < KK) ? bestd[h] : INFINITY;
        int ii = (h < KK) ? besti[h] : 0x7fffffff;
        float d0 = dd; int i0 = ii;
#pragma unroll
        for (int off = 32; off > 0; off >>= 1) {
            float od = __shfl_xor(dd, off);
            int oi = __shfl_xor(ii, off);
            if (od < dd || (od == dd && oi < ii)) { dd = od; ii = oi; }
        }
        if (lane == s) mywin = ii;
        if (h < KK && i0 == ii && d0 == dd) h++;
    }
    if (lane < KK) idx[(size_t)row * KK + lane] = mywin;
}

// ---------------------------------------------------------------------------
// MFMA GEMM (validated rounds 16/17/20, verbatim): single-pass 4-tile staging
// + XOR swizzle. LDS 32 KB. Used for layers 0,1,2,4 (full-GPU 128^2 grids).
__global__ __launch_bounds__(256) void gemm2_mfma_kernel(
        const unsigned short* __restrict__ XSh, const unsigned short* __restrict__ XSl,
        const unsigned short* __restrict__ WT, const float* __restrict__ bias,
        float* __restrict__ Aout, float* __restrict__ Tout, int fin, int fout) {
    int m0 = blockIdx.x * 128;
    int n0 = blockIdx.y * 128;
    __shared__ __align__(16) unsigned short AsB[4 * 128 * 32];   // 32 KB
    unsigned short* Ah = AsB;
    unsigned short* Al = Ah + 128 * 32;
    unsigned short* Bh = Al + 128 * 32;
    unsigned short* Bl = Bh + 128 * 32;

    int tid = threadIdx.x;
    int lane = tid & 63;
    int wave = tid >> 6;
    int wr = (wave >> 1) * 64, wc = (wave & 1) * 64;
    int l15 = lane & 15, kq = lane >> 4;
    int rsub = lane >> 2;
    int csub = (((lane & 3) ^ ((lane >> 3) & 3))) * 8;
    int kqs = (kq ^ ((l15 >> 1) & 3)) * 8;
    int w2f = 2 * fin;

    f32x4 acc[4][4];
#pragma unroll
    for (int mt = 0; mt < 4; ++mt)
#pragma unroll
        for (int nt = 0; nt < 4; ++nt) acc[mt][nt] = (f32x4){0.f, 0.f, 0.f, 0.f};

    for (int kc = 0; kc < fin; kc += 32) {
        __syncthreads();
#pragma unroll
        for (int j = 0; j < 2; ++j) {
            int row = wave * 32 + j * 16 + rsub;
            int dsto = wave * 1024 + j * 512;
            async16(XSh + (size_t)(m0 + row) * fin + kc + csub, Ah + dsto);
            async16(XSl + (size_t)(m0 + row) * fin + kc + csub, Al + dsto);
            async16(WT + (size_t)(n0 + row) * w2f + kc + csub, Bh + dsto);
            async16(WT + (size_t)(n0 + row) * w2f + fin + kc + csub, Bl + dsto);
        }
        __syncthreads();
        bf16x8 bh[4], bl[4];
#pragma unroll
        for (int t = 0; t < 4; ++t) {
            bh[t] = *(const bf16x8*)&Bh[(wc + t * 16 + l15) * 32 + kqs];
            bl[t] = *(const bf16x8*)&Bl[(wc + t * 16 + l15) * 32 + kqs];
        }
#pragma unroll
        for (int mt = 0; mt < 4; ++mt) {
            bf16x8 ah = *(const bf16x8*)&Ah[(wr + mt * 16 + l15) * 32 + kqs];
            bf16x8 al = *(const bf16x8*)&Al[(wr + mt * 16 + l15) * 32 + kqs];
#pragma unroll
            for (int nt = 0; nt < 4; ++nt) {
                acc[mt][nt] = __builtin_amdgcn_mfma_f32_16x16x32_bf16(ah, bh[nt], acc[mt][nt], 0, 0, 0);
                acc[mt][nt] = __builtin_amdgcn_mfma_f32_16x16x32_bf16(al, bh[nt], acc[mt][nt], 0, 0, 0);
                acc[mt][nt] = __builtin_amdgcn_mfma_f32_16x16x32_bf16(ah, bl[nt], acc[mt][nt], 0, 0, 0);
            }
        }
    }
#pragma unroll
    for (int mt = 0; mt < 4; ++mt) {
        int mbase = m0 + wr + mt * 16 + kq * 4;
#pragma unroll
        for (int nt = 0; nt < 4; ++nt) {
            int oc = n0 + wc + nt * 16 + l15;
            f32x4 c = acc[mt][nt];
            if (oc < fout) {
                float bv = bias[oc];
#pragma unroll
                for (int r = 0; r < 4; ++r)
                    Aout[(size_t)(mbase + r) * fout + oc] = c[r] + bv;
            } else {
                int o2 = oc - fout;
#pragma unroll
                for (int r = 0; r < 4; ++r)
                    Tout[(size_t)(mbase + r) * fout + o2] = c[r];
            }
        }
    }
}

// ---------------------------------------------------------------------------
// 256^2-tile 8-phase pipelined GEMM (round-1 verbatim, refcheck'd) — layer 3
// only (grid 256 = 1 block/CU; measured best at l3 in R5).
__device__ __forceinline__ const unsigned short* tbaseA(
        const unsigned short* XSh, const unsigned short* XSl, int F, int t) {
    int ko = t * 64;
    if (ko < F) return XSh + ko;
    if (ko < 2 * F) return XSl + (ko - F);
    return XSh + (ko - 2 * F);
}
__device__ __forceinline__ const unsigned short* tbaseB(
        const unsigned short* WT, int F, int t) {
    int ko = t * 64;
    if (ko < F) return WT + ko;
    if (ko < 2 * F) return WT + (ko - F);       // hi again
    return WT + F + (ko - 2 * F);               // lo half of the row
}

#define GBAR() asm volatile("s_barrier" ::: "memory")

__global__ __launch_bounds__(512, 2) void gemm2_8ph_kernel(
        const unsigned short* __restrict__ XSh, const unsigned short* __restrict__ XSl,
        const unsigned short* __restrict__ WT, const float* __restrict__ bias,
        float* __restrict__ Aout, float* __restrict__ Tout, int F, int fout, int nby) {
    __shared__ __align__(16) unsigned short Lds[65536];   // 128 KiB

    int nwg = gridDim.x;
    int bid = blockIdx.x;
    int q = nwg >> 3;
    int swz = (bid & 7) * q + (bid >> 3);
    int by = swz % nby;
    int bx = swz / nby;
    int m0 = bx * 256, n0 = by * 256;

    int tid = threadIdx.x;
    int lane = tid & 63;
    int wave = tid >> 6;
    int mw = wave >> 2;
    int nw = wave & 3;
    int l15 = lane & 15, kq = lane >> 4;
    int rx7 = l15 & 7;

    int isA = (wave < 4);
    size_t rowmul = isA ? (size_t)F : (size_t)(2 * F);
    int orgn = isA ? m0 : n0;
    int r8 = lane >> 3;
    int cb8 = ((lane & 7) ^ r8) * 8;
    int subb = (wave & 3) * 8;
    int ldsoA = isA ? 0 : 16384;

    int nt = (3 * F) >> 6;

    f32x4 acc[8][4];
#pragma unroll
    for (int mt = 0; mt < 8; ++mt)
#pragma unroll
        for (int nn = 0; nn < 4; ++nn) acc[mt][nn] = (f32x4){0.f, 0.f, 0.f, 0.f};

    auto stage = [&](const unsigned short* tb, int par, int j) {
        int sub = subb + j;
        async16(tb + (size_t)(orgn + sub * 8 + r8) * rowmul + cb8,
                Lds + par * 32768 + ldsoA + sub * 512);
    };

    {
        const unsigned short* t0 = isA ? tbaseA(XSh, XSl, F, 0) : tbaseB(WT, F, 0);
        const unsigned short* t1 = isA ? tbaseA(XSh, XSl, F, 1) : tbaseB(WT, F, 1);
#pragma unroll
        for (int j = 0; j < 8; ++j) stage(t0, 0, j);
#pragma unroll
        for (int j = 0; j < 4; ++j) stage(t1, 1, j);
    }
    asm volatile("s_waitcnt vmcnt(4)" ::: "memory");
    GBAR();

    for (int t = 0; t < nt; ++t) {
        const unsigned short* Ab = Lds + (t & 1) * 32768;
        const unsigned short* Bb = Ab + 16384;
        bool s1 = (t + 1 < nt), s2 = (t + 2 < nt);
        const unsigned short* tb1 = s1 ? (isA ? tbaseA(XSh, XSl, F, t + 1)
                                              : tbaseB(WT, F, t + 1)) : XSh;
        const unsigned short* tb2 = s2 ? (isA ? tbaseA(XSh, XSl, F, t + 2)
                                              : tbaseB(WT, F, t + 2)) : XSh;
        int p1 = (t + 1) & 1, p0 = t & 1;

        bf16x8 aF[4][2], bA[2][2], bB[2][2];

#pragma unroll
        for (int mt = 0; mt < 4; ++mt)
#pragma unroll
            for (int kf = 0; kf < 2; ++kf)
                aF[mt][kf] = *(const bf16x8*)&Ab[(mw * 128 + mt * 16 + l15) * 64 +
                                                 ((kf * 4 + kq) ^ rx7) * 8];
#pragma unroll
        for (int nn = 0; nn < 2; ++nn)
#pragma unroll
            for (int kf = 0; kf < 2; ++kf)
                bA[nn][kf] = *(const bf16x8*)&Bb[(nw * 64 + nn * 16 + l15) * 64 +
                                                 ((kf * 4 + kq) ^ rx7) * 8];
        if (s1) { stage(tb1, p1, 4); stage(tb1, p1, 5); }
        GBAR();
        __builtin_amdgcn_s_setprio(1);
#pragma unroll
        for (int mt = 0; mt < 4; ++mt)
#pragma unroll
            for (int nn = 0; nn < 2; ++nn) {
                acc[mt][nn] = __builtin_amdgcn_mfma_f32_16x16x32_bf16(aF[mt][0], bA[nn][0], acc[mt][nn], 0, 0, 0);
                acc[mt][nn] = __builtin_amdgcn_mfma_f32_16x16x32_bf16(aF[mt][1], bA[nn][1], acc[mt][nn], 0, 0, 0);
            }
        __builtin_amdgcn_s_setprio(0);
        GBAR();

#pragma unroll
        for (int nn = 0; nn < 2; ++nn)
#pragma unroll
            for (int kf = 0; kf < 2; ++kf)
                bB[nn][kf] = *(const bf16x8*)&Bb[(nw * 64 + (nn + 2) * 16 + l15) * 64 +
                                                 ((kf * 4 + kq) ^ rx7) * 8];
        if (s1) { stage(tb1, p1, 6); stage(tb1, p1, 7); }
        GBAR();
        __builtin_amdgcn_s_setprio(1);
#pragma unroll
        for (int mt = 0; mt < 4; ++mt)
#pragma unroll
            for (int nn = 0; nn < 2; ++nn) {
                acc[mt][nn + 2] = __builtin_amdgcn_mfma_f32_16x16x32_bf16(aF[mt][0], bB[nn][0], acc[mt][nn + 2], 0, 0, 0);
                acc[mt][nn + 2] = __builtin_amdgcn_mfma_f32_16x16x32_bf16(aF[mt][1], bB[nn][1], acc[mt][nn + 2], 0, 0, 0);
            }
        __builtin_amdgcn_s_setprio(0);
        GBAR();

#pragma unroll
        for (int mt = 0; mt < 4; ++mt)
#pragma unroll
            for (int kf = 0; kf < 2; ++kf)
                aF[mt][kf] = *(const bf16x8*)&Ab[(mw * 128 + (mt + 4) * 16 + l15) * 64 +
                                                 ((kf * 4 + kq) ^ rx7) * 8];
        GBAR();
        __builtin_amdgcn_s_setprio(1);
#pragma unroll
        for (int mt = 0; mt < 4; ++mt)
#pragma unroll
            for (int nn = 0; nn < 2; ++nn) {
                acc[mt + 4][nn] = __builtin_amdgcn_mfma_f32_16x16x32_bf16(aF[mt][0], bA[nn][0], acc[mt + 4][nn], 0, 0, 0);
                acc[mt + 4][nn] = __builtin_amdgcn_mfma_f32_16x16x32_bf16(aF[mt][1], bA[nn][1], acc[mt + 4][nn], 0, 0, 0);
            }
        __builtin_amdgcn_s_setprio(0);
        GBAR();

        if (s2) { stage(tb2, p0, 0); stage(tb2, p0, 1); stage(tb2, p0, 2); stage(tb2, p0, 3); }
        GBAR();
        __builtin_amdgcn_s_setprio(1);
#pragma unroll
        for (int mt = 0; mt < 4; ++mt)
#pragma unroll
            for (int nn = 0; nn < 2; ++nn) {
                acc[mt + 4][nn + 2] = __builtin_amdgcn_mfma_f32_16x16x32_bf16(aF[mt][0], bB[nn][0], acc[mt + 4][nn + 2], 0, 0, 0);
                acc[mt + 4][nn + 2] = __builtin_amdgcn_mfma_f32_16x16x32_bf16(aF[mt][1], bB[nn][1], acc[mt + 4][nn + 2], 0, 0, 0);
            }
        __builtin_amdgcn_s_setprio(0);
        if (s2)      asm volatile("s_waitcnt vmcnt(4)" ::: "memory");
        else if (s1) asm volatile("s_waitcnt vmcnt(0)" ::: "memory");
        GBAR();
    }

#pragma unroll
    for (int mt = 0; mt < 8; ++mt) {
        int mbase = m0 + mw * 128 + mt * 16 + kq * 4;
#pragma unroll
        for (int nn = 0; nn < 4; ++nn) {
            int oc = n0 + nw * 64 + nn * 16 + l15;
            f32x4 c = acc[mt][nn];
            if (oc < fout) {
                float bv = bias[oc];
#pragma unroll
                for (int r = 0; r < 4; ++r)
                    Aout[(size_t)(mbase + r) * fout + oc] = c[r] + bv;
            } else {
                int o2 = oc - fout;
#pragma unroll
                for (int r = 0; r < 4; ++r)
                    Tout[(size_t)(mbase + r) * fout + o2] = c[r];
            }
        }
    }
}

// ---------------------------------------------------------------------------
// FUSED gathermax (layers 0-3): wave-per-row; writes bf16 splits + sq only.
__global__ __launch_bounds__(256) void gathermax_fused_kernel(
        const float* __restrict__ A, const float* __restrict__ T,
        const int* __restrict__ idx, unsigned short* __restrict__ hi,
        unsigned short* __restrict__ lo, float* __restrict__ sq, int shift) {
    int b = blockIdx.y;
    int wave = threadIdx.x >> 6;
    int lane = threadIdx.x & 63;
    int pnl = blockIdx.x * 4 + wave;
    int pn = (b << 11) + pnl;
    int fout = 1 << shift;
    int nf4 = fout >> 2;
    const float* Tb = T + ((size_t)b << 11) * fout;
    const int* ip = idx + (size_t)pn * KK;
    int j[KK];
#pragma unroll
    for (int k = 0; k < KK; ++k) j[k] = ip[k];

    float s = 0.f;
    for (int f4 = lane; f4 < nf4; f4 += 64) {
        int o = f4 * 4;
        float4 m = {-INFINITY, -INFINITY, -INFINITY, -INFINITY};
#pragma unroll
        for (int k = 0; k < KK; ++k) {
            float4 t = *(const float4*)&Tb[(size_t)j[k] * fout + o];
            m.x = fmaxf(m.x, t.x); m.y = fmaxf(m.y, t.y);
            m.z = fmaxf(m.z, t.z); m.w = fmaxf(m.w, t.w);
        }
        float4 a = *(const float4*)&A[(size_t)pn * fout + o];
        float h4[4];
        h4[0] = a.x + m.x; h4[1] = a.y + m.y; h4[2] = a.z + m.z; h4[3] = a.w + m.w;
        uint2 uh, ul;
        unsigned short hs[4], ls[4];
#pragma unroll
        for (int q = 0; q < 4; ++q) {
            float h = h4[q] > 0.f ? h4[q] : 0.2f * h4[q];
            s += h * h;
            unsigned short hh = f2bf(h);
            hs[q] = hh;
            ls[q] = f2bf(h - bf2f(hh));
        }
        uh.x = (unsigned)hs[0] | ((unsigned)hs[1] << 16);
        uh.y = (unsigned)hs[2] | ((unsigned)hs[3] << 16);
        ul.x = (unsigned)ls[0] | ((unsigned)ls[1] << 16);
        ul.y = (unsigned)ls[2] | ((unsigned)ls[3] << 16);
        *(uint2*)&hi[(size_t)pn * fout + o] = uh;
        *(uint2*)&lo[(size_t)pn * fout + o] = ul;
    }
#pragma unroll
    for (int off = 32; off > 0; off >>= 1) s += __shfl_down(s, off);
    if (lane == 0) sq[pn] = s;
}

// ---------------------------------------------------------------------------
// FUSED l4 gathermax + gmax pass 1 (validated round 20).
__global__ __launch_bounds__(256) void gathermax_gmax_kernel(
        const float* __restrict__ A, const float* __restrict__ T,
        const int* __restrict__ idx, float* __restrict__ gp) {
    int chunk = blockIdx.x;
    int b = blockIdx.y;
    int o = threadIdx.x * 4;
    const float* Tb = T + ((size_t)b << 11) * 1024;
    float4 gm = {-INFINITY, -INFINITY, -INFINITY, -INFINITY};
    for (int p = 0; p < NN / GCH; ++p) {
        int pnl = chunk * (NN / GCH) + p;
        int pn = (b << 11) + pnl;
        const int* ip = idx + (size_t)pn * KK;
        float4 m = {-INFINITY, -INFINITY, -INFINITY, -INFINITY};
#pragma unroll
        for (int k = 0; k < KK; ++k) {
            int j = ip[k];
            float4 t = *(const float4*)&Tb[(size_t)j * 1024 + o];
            m.x = fmaxf(m.x, t.x); m.y = fmaxf(m.y, t.y);
            m.z = fmaxf(m.z, t.z); m.w = fmaxf(m.w, t.w);
        }
        float4 a = *(const float4*)&A[(size_t)pn * 1024 + o];
        float4 h;
        h.x = a.x + m.x; h.y = a.y + m.y; h.z = a.z + m.z; h.w = a.w + m.w;
        h.x = h.x > 0.f ? h.x : 0.2f * h.x;
        h.y = h.y > 0.f ? h.y : 0.2f * h.y;
        h.z = h.z > 0.f ? h.z : 0.2f * h.z;
        h.w = h.w > 0.f ? h.w : 0.2f * h.w;
        gm.x = fmaxf(gm.x, h.x); gm.y = fmaxf(gm.y, h.y);
        gm.z = fmaxf(gm.z, h.z); gm.w = fmaxf(gm.w, h.w);
    }
    *(float4*)&gp[((size_t)chunk * BB + b) * 1024 + o] = gm;
}

// ---------------------------------------------------------------------------
// Parallel tail: gmax2 (coalesced) then wave-per-output MLP stages.
__global__ void gmax2_kernel(const float* __restrict__ gp, float* __restrict__ g) {
    int i = blockIdx.x * 256 + threadIdx.x;      // 0..8191
    int b = i >> 10, o = i & 1023;
    float m = -INFINITY;
    for (int c = 0; c < GCH; ++c) m = fmaxf(m, gp[((size_t)c * BB + b) * 1024 + o]);
    g[(size_t)b * 1024 + o] = m;
}

// one wave per (b,t): H1[b][t] = m0b[t] + dot(G[b], m0w[:,t])   (1024 waves)
__global__ __launch_bounds__(256) void mlp1_kernel(
        const float* __restrict__ g, const float* __restrict__ m0w,
        const float* __restrict__ m0b, float* __restrict__ H1) {
    int wid = blockIdx.x * 4 + (threadIdx.x >> 6);
    int lane = threadIdx.x & 63;
    int b = wid >> 7, t = wid & 127;
    float s = 0.f;
    for (int f = lane; f < 1024; f += 64)
        s += g[(size_t)b * 1024 + f] * m0w[(size_t)f * 128 + t];
#pragma unroll
    for (int off = 32; off > 0; off >>= 1) s += __shfl_down(s, off);
    if (lane == 0) H1[(size_t)b * 128 + t] = s + m0b[t];
}

// one wave per (b,t): H2[b][t] = m1b[t] + dot(H1[b], m1w[:,t])   (512 waves)
__global__ __launch_bounds__(256) void mlp2_kernel(
        const float* __restrict__ H1, const float* __restrict__ m1w,
        const float* __restrict__ m1b, float* __restrict__ H2) {
    int wid = blockIdx.x * 4 + (threadIdx.x >> 6);
    int lane = threadIdx.x & 63;
    int b = wid >> 6, t = wid & 63;
    float s = 0.f;
    for (int f = lane; f < 128; f += 64)
        s += H1[(size_t)b * 128 + f] * m1w[(size_t)f * 64 + t];
#pragma unroll
    for (int off = 32; off > 0; off >>= 1) s += __shfl_down(s, off);
    if (lane == 0) H2[(size_t)b * 64 + t] = s + m1b[t];
}

// one wave per b: out[b] = m2b[0] + dot(H2[b], m2w)   (8 waves)
__global__ __launch_bounds__(256) void mlp3_kernel(
        const float* __restrict__ H2, const float* __restrict__ m2w,
        const float* __restrict__ m2b, float* __restrict__ out) {
    int b = blockIdx.x * 4 + (threadIdx.x >> 6);
    int lane = threadIdx.x & 63;
    if (b >= BB) return;
    float s = H2[(size_t)b * 64 + lane] * m2w[lane];
#pragma unroll
    for (int off = 32; off > 0; off >>= 1) s += __shfl_down(s, off);
    if (lane == 0) out[b] = s + m2b[0];
}

// ---------------------------------------------------------------------------
extern "C" void kernel_launch(void* const* d_in, const int* in_sizes, int n_in,
                              void* d_out, int out_size, void* d_ws, size_t ws_size,
                              hipStream_t stream) {
    const float* x0 = (const float*)d_in[0];
    const float* w[5], * bi[5];
    for (int i = 0; i < 5; ++i) { w[i] = (const float*)d_in[1 + 2 * i]; bi[i] = (const float*)d_in[2 + 2 * i]; }
    const float* m0w = (const float*)d_in[11]; const float* m0b = (const float*)d_in[12];
    const float* m1w = (const float*)d_in[13]; const float* m1b = (const float*)d_in[14];
    const float* m2w = (const float*)d_in[15]; const float* m2b = (const float*)d_in[16];

    const int fouts[5] = {64, 128, 256, 512, 1024};
    const int shifts[5] = {6, 7, 8, 9, 10};
    const int woff[5] = {0, 8192, 40960, 172032, 696320};
    const size_t WTALL = 2793472;   // shorts

    float* X0 = (float*)d_ws;
    float* X1 = X0 + (size_t)BN * 1024;
    float* T  = X1 + (size_t)BN * 1024;
    float* SQ = T  + (size_t)BN * 1024;
    int*   IDX = (int*)(SQ + BN);
    unsigned short* XSh = (unsigned short*)(IDX + (size_t)BN * KK);
    unsigned short* XSl = XSh + (size_t)BN * 512;
    unsigned short* WTall = XSl + (size_t)BN * 512;
    float* GP = (float*)(WTall + WTALL);
    float* G  = GP + (size_t)GCH * BB * 1024;
    float* H1 = G + (size_t)BB * 1024;
    float* H2 = H1 + (size_t)BB * 128;
    float* bufs[2] = {X0, X1};

    xsplit3_kernel<<<(BN + 255) / 256, 256, 0, stream>>>(x0, XSh, XSl, SQ);
    wsplit_all_kernel<<<(1396736 + 255) / 256, 256, 0, stream>>>(w[0], w[1], w[2], w[3], w[4], WTall);

    // layer-0 kNN: direct 3-D distance select (no d2 materialization)
    knn_sel0_kernel<<<BN / 4, 256, 0, stream>>>(x0, IDX);

    int fin = 3;
    for (int l = 0; l < 5; ++l) {
        int fout = fouts[l];
        float* nxt = bufs[l & 1];
        int Fg = (l == 0) ? 32 : fin;      // padded K for MFMA path

        if (l > 0) {
            // d2 halves: D2a = T, D2b = nxt (both dead until gemm2 writes)
            dim3 gg2(136, BB);   // upper-triangle 128x128 tile pairs
            knn_gram_kernel<<<gg2, 256, 0, stream>>>(XSh, XSl, SQ, T, nxt, Fg);
            knn_select_kernel<<<BN / 4, 256, 0, stream>>>(T, nxt, IDX);
        }

        if (l == 3) {
            // 256^2-tile pipelined GEMM (K' = 3*fin via K-concat); grid 256
            // blocks = 1/CU. l2 would only fill half the CUs at this tile;
            // l4 measured faster on the 128^2 kernel (113 vs 120 us).
            int nby = (2 * fout) / 256;
            gemm2_8ph_kernel<<<dim3(64 * nby), 512, 0, stream>>>(
                XSh, XSl, WTall + woff[l], bi[l], nxt, T, fin, fout, nby);
        } else {
            dim3 gg(BN / 128, (2 * fout) / 128);
            gemm2_mfma_kernel<<<gg, 256, 0, stream>>>(XSh, XSl, WTall + woff[l], bi[l], nxt, T, Fg, fout);
        }

        if (l < 4) {
            dim3 gmg(NN / 4, BB);
            gathermax_fused_kernel<<<gmg, 256, 0, stream>>>(nxt, T, IDX, XSh, XSl, SQ, shifts[l]);
        } else {
            dim3 gmg(GCH, BB);
            gathermax_gmax_kernel<<<gmg, 256, 0, stream>>>(nxt, T, IDX, GP);
        }

        fin = fout;
    }

    gmax2_kernel<<<32, 256, 0, stream>>>(GP, G);
    mlp1_kernel<<<256, 256, 0, stream>>>(G, m0w, m0b, H1);
    mlp2_kernel<<<128, 256, 0, stream>>>(H1, m1w, m1b, H2);
    mlp3_kernel<<<2, 256, 0, stream>>>(H2, m2w, m2b, (float*)d_out);
}